// Round 16
// baseline (294.846 us; speedup 1.0000x reference)
//
#include <hip/hip_runtime.h>
#include <math.h>

#define B_ 4
#define C_ 256
#define L_ 4096
#define E_ 256
#define NH_ 8
#define HD_ 32
#define TOPK_ 512
#define MLP_ 1024
#define EPS_ 1e-5f

typedef __attribute__((ext_vector_type(4))) float f32x4;
typedef __attribute__((ext_vector_type(8))) short short8;
typedef __attribute__((ext_vector_type(2))) unsigned int u32x2;
typedef __attribute__((ext_vector_type(4))) unsigned int u32x4;

// async global->LDS, 16B per lane; LDS dest must be linear in lane order (wave base + lane*16).
#define GLOAD_LDS(srcp, ldsp)                                                                     \
  __builtin_amdgcn_global_load_lds((const __attribute__((address_space(1))) void*)(srcp),         \
                                   (__attribute__((address_space(3))) void*)(ldsp), 16, 0, 0)

__device__ __forceinline__ unsigned short f2bf(float x) {
  unsigned u = __float_as_uint(x);
  return (unsigned short)((u + 0x7FFFu + ((u >> 16) & 1)) >> 16);
}
__device__ __forceinline__ float bf2f(unsigned short h) { return __uint_as_float((unsigned)h << 16); }

// 16-lane sum via DPP row rotations (fused v_add_f32_dpp: 1 VALU/level, zero DS-pipe use)
__device__ __forceinline__ float dpp_red16(float s) {
  s += __int_as_float(__builtin_amdgcn_update_dpp(0, __float_as_int(s), 0x121, 0xF, 0xF, false));  // row_ror:1
  s += __int_as_float(__builtin_amdgcn_update_dpp(0, __float_as_int(s), 0x122, 0xF, 0xF, false));  // row_ror:2
  s += __int_as_float(__builtin_amdgcn_update_dpp(0, __float_as_int(s), 0x124, 0xF, 0xF, false));  // row_ror:4
  s += __int_as_float(__builtin_amdgcn_update_dpp(0, __float_as_int(s), 0x128, 0xF, 0xF, false));  // row_ror:8
  return s;
}

__device__ __forceinline__ void conv_bf8(const float* __restrict__ W, unsigned short* __restrict__ D, int blk,
                                         int tid) {
  int i = (blk * 256 + tid) * 8;
  float4 x = *(const float4*)(W + i);
  float4 y = *(const float4*)(W + i + 4);
  u32x4 w;
  w.x = (unsigned)f2bf(x.x) | ((unsigned)f2bf(x.y) << 16);
  w.y = (unsigned)f2bf(x.z) | ((unsigned)f2bf(x.w) << 16);
  w.z = (unsigned)f2bf(y.x) | ((unsigned)f2bf(y.y) << 16);
  w.w = (unsigned)f2bf(y.z) | ((unsigned)f2bf(y.w) << 16);
  *(u32x4*)(D + i) = w;
}

// ---------------- fused setup: weight converts + md init + transposes + Qsbuf gather ----------------
// blocks [0,480): prep; [480,4576): transpose qs_in -> Qt_bf (bf16 only; fp32 Qt eliminated);
// [4576,8672): ctx_in -> Kt fp32; [8672,9184): gather Qsbuf[b][r][:] = qs_in[b][:][rind[b][r]]
// (scattered 4B reads; qs_in is L3-resident from the co-running transpose blocks).
__global__ __launch_bounds__(256) void k_setup(const float* __restrict__ ipw, const float* __restrict__ opw,
                                               const float* __restrict__ c1w, const float* __restrict__ c2w,
                                               const float* __restrict__ qs_in, const float* __restrict__ ctx_in,
                                               const int* __restrict__ rind,
                                               unsigned short* __restrict__ wq_bf, unsigned short* __restrict__ wkv_bf,
                                               unsigned short* __restrict__ c1w_bf, unsigned short* __restrict__ c2w_bf,
                                               unsigned short* __restrict__ opw_d, unsigned* __restrict__ md,
                                               unsigned short* __restrict__ Qt_bf, float* __restrict__ Kt,
                                               float* __restrict__ Qsbuf) {
  __shared__ float tile[32][33];
  const int bx = blockIdx.x;
  const int tid = threadIdx.x;
  if (bx < 480) {
    if (bx < 32) {
      conv_bf8(ipw, wq_bf, bx, tid);
    } else if (bx < 96) {
      conv_bf8(ipw + 65536, wkv_bf, bx - 32, tid);
    } else if (bx < 224) {
      conv_bf8(c1w, c1w_bf, bx - 96, tid);
    } else if (bx < 352) {
      conv_bf8(c2w, c2w_bf, bx - 224, tid);
    } else if (bx < 416) {
      int i = ((bx - 352) * 256 + tid) * 4;
      int k = i & 255;
      int n = i >> 8;
      float4 x = *(const float4*)(opw + i);
      unsigned short h0 = f2bf(x.x), h1 = f2bf(x.y), h2 = f2bf(x.z), h3 = f2bf(x.w);
      unsigned short l0 = f2bf(x.x - bf2f(h0)), l1 = f2bf(x.y - bf2f(h1));
      unsigned short l2 = f2bf(x.z - bf2f(h2)), l3 = f2bf(x.w - bf2f(h3));
      u32x2 hv, lv;
      hv.x = (unsigned)h0 | ((unsigned)h1 << 16); hv.y = (unsigned)h2 | ((unsigned)h3 << 16);
      lv.x = (unsigned)l0 | ((unsigned)l1 << 16); lv.y = (unsigned)l2 | ((unsigned)l3 << 16);
      unsigned short* dst = opw_d + (long)n * 512 + (k >> 5) * 64 + (k & 31);
      *(u32x2*)dst = hv;
      *(u32x2*)(dst + 32) = lv;
    } else {
      md[(bx - 416) * 256 + tid] = 0x7f800000u;
    }
    return;
  }
  if (bx >= 8672) {  // Qsbuf gather: one 64-lane group per selected row
    int gr = (bx - 8672) * 4 + (tid >> 6);
    int b = gr >> 9, r = gr & 511;
    int idx = rind[b * TOPK_ + r];
    int c0 = (tid & 63) * 4;
    float* dst = Qsbuf + ((long)b * TOPK_ + r) * C_ + c0;
    const float* src = qs_in + (long)b * C_ * L_ + idx;
#pragma unroll
    for (int i = 0; i < 4; i++) dst[i] = src[(long)(c0 + i) * L_];
    return;
  }
  int tb = bx - 480;
  const float* in;
  float* out;
  unsigned short* outbf;
  int wbf;
  if (tb < 4096) {
    in = qs_in; out = nullptr; outbf = Qt_bf; wbf = 1;
  } else {
    tb -= 4096; in = ctx_in; out = Kt; outbf = nullptr; wbf = 0;
  }
  const int x = tb & 127, y = (tb >> 7) & 7, b = tb >> 10;
  const int l0 = x * 32, c0 = y * 32;
  const int tx = tid & 31, ty = tid >> 5;
  const float* ib = in + (long)b * C_ * L_;
#pragma unroll
  for (int i = ty; i < 32; i += 8) tile[i][tx] = ib[(long)(c0 + i) * L_ + l0 + tx];
  __syncthreads();
#pragma unroll
  for (int i = ty; i < 32; i += 8) {
    float v = tile[tx][i];
    long off = (long)(l0 + i) * C_ + c0 + tx;
    if (wbf) outbf[(long)b * L_ * C_ + off] = f2bf(v);
    else out[(long)b * L_ * C_ + off] = v;
  }
}

// ---------------- gather_bf (post-selection) ----------------
__global__ __launch_bounds__(256) void k_gather_bf(const float* __restrict__ src, const int* __restrict__ ind,
                                                   unsigned short* __restrict__ dst, int nrows) {
  int gr = blockIdx.x * 4 + (threadIdx.x >> 6);
  int b = gr / nrows, r = gr % nrows;
  int c = (threadIdx.x & 63) * 4;
  int idx = ind[b * nrows + r];
  float4 x = *(const float4*)(src + ((long)b * L_ + idx) * C_ + c);
  u32x2 w;
  w.x = (unsigned)f2bf(x.x) | ((unsigned)f2bf(x.y) << 16);
  w.y = (unsigned)f2bf(x.z) | ((unsigned)f2bf(x.w) << 16);
  *(u32x2*)(dst + ((long)b * nrows + r) * C_ + c) = w;
}

// ---------------- merged: q-projection (512 blocks, FIRST) + min-L1 distance (2048 blocks) ----------------
// q-proj is independent of the dist->select chain (needs only Qt_bf); dist is VALU-bound at
// ~42% occupancy with idle MFMA pipes -> co-scheduled qproj blocks ride the matrix pipe free
// (m114: MFMA/VALU waves overlap, time ~ max not sum). LDS union: dist 16.25KB | gemm 24KB.
__global__ __launch_bounds__(256) void k_dist_qp(const float* __restrict__ Kt, const float* __restrict__ Qs,
                                                 unsigned* __restrict__ mdbits,
                                                 const unsigned short* __restrict__ Aq,
                                                 const unsigned short* __restrict__ Bw,
                                                 unsigned short* __restrict__ q_bf,
                                                 const float* __restrict__ bias, float cscale) {
  __shared__ __align__(16) char smem[24832];
  const int tid = threadIdx.x;
  if (blockIdx.x < 512) {
    // ---- q-proj: C[m,n] = (sum_k Aq[m,k]*Bw[n,k] + bias[n]) * cscale -> bf16 (BN=64 tile)
    char* AsB = smem;           // 128x64 bf16 = 16KB
    char* BsB = smem + 16384;   // 64x64 bf16 = 8KB
    const int bxx = blockIdx.x;
    const int bx_n = bxx & 3, by_m = bxx >> 2;
    const int wid = tid >> 6, lane = tid & 63, lr = lane & 15, lg = lane >> 4;
    const int row0 = wid * 32;
    f32x4 acc[2][4];
#pragma unroll
    for (int m = 0; m < 2; m++)
#pragma unroll
      for (int n = 0; n < 4; n++) acc[m][n] = (f32x4){0.f, 0.f, 0.f, 0.f};
    for (int k0 = 0; k0 < 256; k0 += 64) {
      if (k0) __syncthreads();
#pragma unroll
      for (int j = 0; j < 4; j++) {
        int gix = j * 256 + tid;
        int r = gix >> 3, s = gix & 7;
        int csrc = s ^ (r & 7);
        GLOAD_LDS(Aq + (long)(by_m * 128 + r) * 256 + k0 + csrc * 8, AsB + gix * 16);
      }
#pragma unroll
      for (int j = 0; j < 2; j++) {
        int gix = j * 256 + tid;
        int r = gix >> 3, s = gix & 7;
        int csrc = s ^ (r & 7);
        GLOAD_LDS(Bw + (long)(bx_n * 64 + r) * 256 + k0 + csrc * 8, BsB + gix * 16);
      }
      __syncthreads();
      short8 a0[2], a1[2], b0[4], b1[4];
#pragma unroll
      for (int m = 0; m < 2; m++) {
        int rr = row0 + m * 16 + lr;
        a0[m] = *(const short8*)(AsB + rr * 128 + (((0 + lg) ^ (rr & 7)) << 4));
        a1[m] = *(const short8*)(AsB + rr * 128 + (((4 + lg) ^ (rr & 7)) << 4));
      }
#pragma unroll
      for (int n = 0; n < 4; n++) {
        int rr = n * 16 + lr;
        b0[n] = *(const short8*)(BsB + rr * 128 + (((0 + lg) ^ (rr & 7)) << 4));
        b1[n] = *(const short8*)(BsB + rr * 128 + (((4 + lg) ^ (rr & 7)) << 4));
      }
#pragma unroll
      for (int m = 0; m < 2; m++)
#pragma unroll
        for (int n = 0; n < 4; n++)
          acc[m][n] = __builtin_amdgcn_mfma_f32_16x16x32_bf16(a0[m], b0[n], acc[m][n], 0, 0, 0);
#pragma unroll
      for (int m = 0; m < 2; m++)
#pragma unroll
        for (int n = 0; n < 4; n++)
          acc[m][n] = __builtin_amdgcn_mfma_f32_16x16x32_bf16(a1[m], b1[n], acc[m][n], 0, 0, 0);
    }
    const int mbase = by_m * 128 + row0 + lg * 4;
    const int nbase = bx_n * 64;
#pragma unroll
    for (int n = 0; n < 4; n++) {
      int nn = nbase + n * 16 + lr;
      float bb = bias[nn];
#pragma unroll
      for (int m = 0; m < 2; m++)
#pragma unroll
        for (int r = 0; r < 4; r++) {
          int mm = mbase + m * 16 + r;
          q_bf[(long)mm * 256 + nn] = f2bf((acc[m][n][r] + bb) * cscale);
        }
    }
    return;
  }
  // ---- dist path (r10/r14 form, best measured 117us)
  const int bxd = blockIdx.x - 512;
  float* Kl = (float*)smem;                       // 16KB
  unsigned* mdl = (unsigned*)(smem + 24576);      // 256B
  const int tb = bxd & 63, b = (bxd >> 6) & 3, qz = bxd >> 8;
  const int cg = tid & 15, qslot = tid >> 4;
  float4 Q[4][4];
  {
    const float* qbase = Qs + ((long)b * TOPK_ + qz * 64 + qslot) * C_ + cg * 4;
#pragma unroll
    for (int r = 0; r < 4; r++)
#pragma unroll
      for (int i = 0; i < 4; i++) Q[r][i] = *(const float4*)(qbase + (long)r * 16 * C_ + i * 64);
  }
#pragma unroll
  for (int r = 0; r < 4; r++) {
    asm volatile("" : "+v"(Q[r][0].x), "+v"(Q[r][0].y), "+v"(Q[r][0].z), "+v"(Q[r][0].w),
                      "+v"(Q[r][1].x), "+v"(Q[r][1].y), "+v"(Q[r][1].z), "+v"(Q[r][1].w));
    asm volatile("" : "+v"(Q[r][2].x), "+v"(Q[r][2].y), "+v"(Q[r][2].z), "+v"(Q[r][2].w),
                      "+v"(Q[r][3].x), "+v"(Q[r][3].y), "+v"(Q[r][3].z), "+v"(Q[r][3].w));
  }
  if (tid < 64) mdl[tid] = 0x7f800000u;
  for (int ck = 0; ck < 4; ck++) {
    __syncthreads();
    {
      const float4* src = (const float4*)(Kt + ((long)b * L_ + tb * 64 + ck * 16) * C_);
      float4* dst = (float4*)Kl;
#pragma unroll
      for (int j = 0; j < 4; j++) dst[tid + j * 256] = src[tid + j * 256];
    }
    __syncthreads();
    for (int t = 0; t < 16; t++) {
      const float* kp = &Kl[t * 256 + cg * 4];
      float4 k0 = *(const float4*)kp;
      float4 k1 = *(const float4*)(kp + 64);
      float4 k2 = *(const float4*)(kp + 128);
      float4 k3 = *(const float4*)(kp + 192);
      float d0, d1, d2, d3;
#define DIST_R(r, dst_)                                                                                   \
  dst_ = (((fabsf(k0.x - Q[r][0].x) + fabsf(k0.y - Q[r][0].y)) +                                          \
           (fabsf(k0.z - Q[r][0].z) + fabsf(k0.w - Q[r][0].w))) +                                         \
          ((fabsf(k1.x - Q[r][1].x) + fabsf(k1.y - Q[r][1].y)) +                                          \
           (fabsf(k1.z - Q[r][1].z) + fabsf(k1.w - Q[r][1].w)))) +                                        \
         (((fabsf(k2.x - Q[r][2].x) + fabsf(k2.y - Q[r][2].y)) +                                          \
           (fabsf(k2.z - Q[r][2].z) + fabsf(k2.w - Q[r][2].w))) +                                         \
          ((fabsf(k3.x - Q[r][3].x) + fabsf(k3.y - Q[r][3].y)) +                                          \
           (fabsf(k3.z - Q[r][3].z) + fabsf(k3.w - Q[r][3].w))))
      DIST_R(0, d0);
      DIST_R(1, d1);
      DIST_R(2, d2);
      DIST_R(3, d3);
#undef DIST_R
      d0 = dpp_red16(d0);
      d1 = dpp_red16(d1);
      d2 = dpp_red16(d2);
      d3 = dpp_red16(d3);
      float mn = fminf(fminf(d0, d1), fminf(d2, d3));
      mn = fminf(mn, __int_as_float(__builtin_amdgcn_ds_swizzle(__float_as_int(mn), 0x401F)));
      if ((tid & 31) == 0) atomicMin(&mdl[ck * 16 + t], __float_as_uint(mn));
    }
  }
  __syncthreads();
  if (tid < 64) atomicMin(&mdbits[(long)b * L_ + tb * 64 + tid], mdl[tid]);
}

// ---------------- exact top-512 selection ----------------
__global__ __launch_bounds__(1024) void k_select(const unsigned* __restrict__ mdb, unsigned* __restrict__ idxsel) {
  __shared__ unsigned vals[4096];
  __shared__ unsigned cnts[32];
  __shared__ unsigned out_n, tie_n;
  __shared__ unsigned short ties[1024];
  const int b = blockIdx.x, tid = threadIdx.x;
  const int lane = tid & 63;
#pragma unroll
  for (int s = 0; s < 4; s++) vals[tid + s * 1024] = mdb[b * 4096 + tid + s * 1024];
  if (tid < 32) cnts[tid] = 0;
  if (tid == 0) { out_n = 0; tie_n = 0; }
  __syncthreads();
  unsigned cur = 0;
  for (int bit = 31; bit >= 0; --bit) {
    unsigned cand = cur | (1u << bit);
    int c = 0;
#pragma unroll
    for (int s = 0; s < 4; s++) {
      unsigned long long bal = __ballot(vals[tid + s * 1024] < cand);
      c += __popcll(bal);
    }
    if (lane == 0) atomicAdd(&cnts[bit], (unsigned)c);
    __syncthreads();
    if (cnts[bit] < 512u) cur = cand;  // uniform: all threads read same LDS value
  }
  const unsigned M = cur;
#pragma unroll
  for (int s = 0; s < 4; s++) {
    int i = tid + s * 1024;
    unsigned v = vals[i];
    if (v < M) {
      unsigned p = atomicAdd(&out_n, 1u);
      idxsel[b * TOPK_ + p] = (unsigned)i;
    } else if (v == M) {
      unsigned t = atomicAdd(&tie_n, 1u);
      if (t < 1024u) ties[t] = (unsigned short)i;
    }
  }
  __syncthreads();
  if (tid == 0) {
    int n1 = (int)out_n;
    int nt = (int)tie_n; if (nt > 1024) nt = 1024;
    int need = 512 - n1; if (need > nt) need = nt;
    for (int j = 0; j < need; j++) {
      int bi = 1 << 30, best = -1;
      for (int t = 0; t < nt; t++) {
        int ix = ties[t];
        if (ix < bi) { bi = ix; best = t; }
      }
      ties[best] = 0xFFFF;  // mark used (> any valid idx)
      idxsel[b * TOPK_ + n1 + j] = (unsigned)bi;
    }
  }
}

// ---------------- single-bf16 MFMA GEMM: C[m,n] = epi(sum_k A[m,k]*B[n,k]) ----------------
// Staging via global_load_lds width=16: LDS dest LINEAR (slot g = row*8 + s), global source
// PRE-SWIZZLED (chunk s ^ (row&7)); swizzled read side unchanged.
// MODE 1: kv dual out. MODE 3: bias+bn+relu -> bf16.
// MODE 5: bias+bn + Xres residual + transposed store -> fp32 out[b][c][l].
template <int BN, int MODE>
__global__ __launch_bounds__(256) void k_gemm_s(
    const unsigned short* __restrict__ A, const unsigned short* __restrict__ Bm, int K, int N, float cscale,
    const float* __restrict__ bias, const float* __restrict__ g, const float* __restrict__ be,
    const float* __restrict__ mu, const float* __restrict__ va, const float* __restrict__ Xres,
    float* __restrict__ Cf, unsigned short* __restrict__ Cb, unsigned short* __restrict__ Caux) {
  constexpr int NWN = (BN == 128) ? 2 : 1;
  constexpr int WR = (NWN == 2) ? 64 : 32;
  constexpr int MG = WR / 16, NG = 4;
  __shared__ __align__(16) unsigned short As[128 * 64];
  __shared__ __align__(16) unsigned short Bs[BN * 64];
  const int tid = threadIdx.x;
  const int wid = tid >> 6, lane = tid & 63, lr = lane & 15, lg = lane >> 4;
  const int wm = wid / NWN, wn = wid % NWN;
  const int row0 = wm * WR, col0 = wn * 64;
  char* AsB = (char*)As;
  char* BsB = (char*)Bs;
  f32x4 acc[MG][NG];
#pragma unroll
  for (int m = 0; m < MG; m++)
#pragma unroll
    for (int n = 0; n < NG; n++) acc[m][n] = (f32x4){0.f, 0.f, 0.f, 0.f};

  for (int k0 = 0; k0 < K; k0 += 64) {
    if (k0) __syncthreads();
    {  // stage A: 1024 16B-chunks, linear LDS, pre-swizzled source
#pragma unroll
      for (int j = 0; j < 4; j++) {
        int gix = j * 256 + tid;
        int r = gix >> 3, s = gix & 7;
        int csrc = s ^ (r & 7);
        const unsigned short* srcp = A + (long)(blockIdx.y * 128 + r) * K + k0 + csrc * 8;
        GLOAD_LDS(srcp, AsB + gix * 16);
      }
    }
    if (BN == 128) {
#pragma unroll
      for (int j = 0; j < 4; j++) {
        int gix = j * 256 + tid;
        int r = gix >> 3, s = gix & 7;
        int csrc = s ^ (r & 7);
        const unsigned short* srcp = Bm + (long)(blockIdx.x * 128 + r) * K + k0 + csrc * 8;
        GLOAD_LDS(srcp, BsB + gix * 16);
      }
    } else {
#pragma unroll
      for (int j = 0; j < 2; j++) {
        int gix = j * 256 + tid;
        int r = gix >> 3, s = gix & 7;
        int csrc = s ^ (r & 7);
        const unsigned short* srcp = Bm + (long)(blockIdx.x * 64 + r) * K + k0 + csrc * 8;
        GLOAD_LDS(srcp, BsB + gix * 16);
      }
    }
    __syncthreads();
    short8 a0[MG], a1[MG], b0[NG], b1[NG];
#pragma unroll
    for (int m = 0; m < MG; m++) {
      int rr = row0 + m * 16 + lr;
      a0[m] = *(const short8*)(AsB + rr * 128 + (((0 + lg) ^ (rr & 7)) << 4));
      a1[m] = *(const short8*)(AsB + rr * 128 + (((4 + lg) ^ (rr & 7)) << 4));
    }
#pragma unroll
    for (int n = 0; n < NG; n++) {
      int rr = col0 + n * 16 + lr;
      b0[n] = *(const short8*)(BsB + rr * 128 + (((0 + lg) ^ (rr & 7)) << 4));
      b1[n] = *(const short8*)(BsB + rr * 128 + (((4 + lg) ^ (rr & 7)) << 4));
    }
#pragma unroll
    for (int m = 0; m < MG; m++)
#pragma unroll
      for (int n = 0; n < NG; n++)
        acc[m][n] = __builtin_amdgcn_mfma_f32_16x16x32_bf16(a0[m], b0[n], acc[m][n], 0, 0, 0);
#pragma unroll
    for (int m = 0; m < MG; m++)
#pragma unroll
      for (int n = 0; n < NG; n++)
        acc[m][n] = __builtin_amdgcn_mfma_f32_16x16x32_bf16(a1[m], b1[n], acc[m][n], 0, 0, 0);
  }
  const int mbase = blockIdx.y * 128 + row0 + lg * 4;
  const int nbase = blockIdx.x * BN + col0;
#pragma unroll
  for (int n = 0; n < NG; n++) {
    int nn = nbase + n * 16 + lr;
    float bb = bias[nn];
    float inv = 0.f, sh = 0.f;
    if (MODE == 3 || MODE == 5) {
      inv = g[nn] / sqrtf(va[nn] + EPS_);
      sh = be[nn] - mu[nn] * inv;
    }
#pragma unroll
    for (int m = 0; m < MG; m++) {
#pragma unroll
      for (int r = 0; r < 4; r++) {
        int mm = mbase + m * 16 + r;
        float v = acc[m][n][r] + bb;
        if (MODE == 1) {
          if (nn < 256) {
            Cb[(long)mm * 256 + nn] = f2bf(v);
          } else {
            int bi = mm >> 9, t = mm & 511;
            Caux[((long)bi * 256 + (nn - 256)) * 512 + t] = f2bf(v);
          }
        } else if (MODE == 3) {
          v = v * inv + sh;
          v = fmaxf(v, 0.f);
          Cb[(long)mm * N + nn] = f2bf(v);
        } else if (MODE == 5) {
          v = v * inv + sh + Xres[(long)mm * 256 + nn];
          int bi = mm >> 12, l = mm & 4095;
          Cf[(long)bi * (C_ * L_) + (long)nn * L_ + l] = v;
        }
      }
    }
  }
}

// ---------------- duo MFMA GEMM (out-proj only): A duo [M][2K], B duo [N][2K] ----------------
__global__ __launch_bounds__(256) void k_gemm_d(const unsigned short* __restrict__ A,
                                                const unsigned short* __restrict__ Bd, int K,
                                                const float* __restrict__ bias, float* __restrict__ Cf,
                                                unsigned short* __restrict__ Cb) {
  constexpr int MG = 2, NG = 4;
  __shared__ __align__(16) unsigned short As[128 * 64];
  __shared__ __align__(16) unsigned short Bs[64 * 64];
  const int tid = threadIdx.x;
  const int wid = tid >> 6, lane = tid & 63, lr = lane & 15, lg = lane >> 4;
  const int row0 = wid * 32;
  char* AsB = (char*)As;
  char* BsB = (char*)Bs;
  f32x4 acc[MG][NG];
#pragma unroll
  for (int m = 0; m < MG; m++)
#pragma unroll
    for (int n = 0; n < NG; n++) acc[m][n] = (f32x4){0.f, 0.f, 0.f, 0.f};

  for (int kb = 0; kb < K; kb += 32) {
    if (kb) __syncthreads();
    {  // A duo: 128 rows x 64 shorts per K-step, row stride 2K
#pragma unroll
      for (int j = 0; j < 4; j++) {
        int gix = j * 256 + tid;
        int r = gix >> 3, s = gix & 7;
        int csrc = s ^ (r & 7);
        const unsigned short* srcp = A + (long)(blockIdx.y * 128 + r) * (2 * K) + kb * 2 + csrc * 8;
        GLOAD_LDS(srcp, AsB + gix * 16);
      }
    }
    {  // B duo: 64 rows x 64 shorts, row stride 2K
#pragma unroll
      for (int j = 0; j < 2; j++) {
        int gix = j * 256 + tid;
        int r = gix >> 3, s = gix & 7;
        int csrc = s ^ (r & 7);
        const unsigned short* srcp = Bd + (long)(blockIdx.x * 64 + r) * (2 * K) + kb * 2 + csrc * 8;
        GLOAD_LDS(srcp, BsB + gix * 16);
      }
    }
    __syncthreads();
    short8 a0[MG], a1[MG], b0[NG], b1[NG];
#pragma unroll
    for (int m = 0; m < MG; m++) {
      int rr = row0 + m * 16 + lr;
      a0[m] = *(const short8*)(AsB + rr * 128 + (((0 + lg) ^ (rr & 7)) << 4));
      a1[m] = *(const short8*)(AsB + rr * 128 + (((4 + lg) ^ (rr & 7)) << 4));
    }
#pragma unroll
    for (int n = 0; n < NG; n++) {
      int rr = n * 16 + lr;
      b0[n] = *(const short8*)(BsB + rr * 128 + (((0 + lg) ^ (rr & 7)) << 4));
      b1[n] = *(const short8*)(BsB + rr * 128 + (((4 + lg) ^ (rr & 7)) << 4));
    }
#pragma unroll
    for (int m = 0; m < MG; m++)
#pragma unroll
      for (int n = 0; n < NG; n++)
        acc[m][n] = __builtin_amdgcn_mfma_f32_16x16x32_bf16(a0[m], b0[n], acc[m][n], 0, 0, 0);
#pragma unroll
    for (int m = 0; m < MG; m++)
#pragma unroll
      for (int n = 0; n < NG; n++)
        acc[m][n] = __builtin_amdgcn_mfma_f32_16x16x32_bf16(a1[m], b0[n], acc[m][n], 0, 0, 0);
#pragma unroll
    for (int m = 0; m < MG; m++)
#pragma unroll
      for (int n = 0; n < NG; n++)
        acc[m][n] = __builtin_amdgcn_mfma_f32_16x16x32_bf16(a0[m], b1[n], acc[m][n], 0, 0, 0);
  }
  const int mbase = blockIdx.y * 128 + row0 + lg * 4;
  const int nbase = blockIdx.x * 64;
#pragma unroll
  for (int n = 0; n < NG; n++) {
    int nn = nbase + n * 16 + lr;
    float bb = bias[nn];
#pragma unroll
    for (int m = 0; m < MG; m++) {
#pragma unroll
      for (int r = 0; r < 4; r++) {
        int mm = mbase + m * 16 + r;
        float v = acc[m][n][r] + bb;
        Cf[(long)mm * 256 + nn] = v;
        Cb[(long)mm * 256 + nn] = f2bf(v);
      }
    }
  }
}

// ---------------- MFMA flash attention; epilogue writes ctx in duo layout ----------------
__global__ __launch_bounds__(256) void k_attn_mfma(const unsigned short* __restrict__ qbf,
                                                   const unsigned short* __restrict__ kvk,
                                                   const unsigned short* __restrict__ vt,
                                                   unsigned short* __restrict__ ctxd) {
  __shared__ __align__(16) unsigned short PT[4 * 1024];
  const int tid = threadIdx.x, wid = tid >> 6, lane = tid & 63, lr = lane & 15, lg = lane >> 4;
  const int b = blockIdx.z, h = blockIdx.y;
  const int q0 = blockIdx.x * 64 + wid * 16;
  char* pt = (char*)(PT + wid * 1024);
  short8 qf = *(const short8*)(qbf + ((long)(b * L_ + q0 + lr)) * E_ + h * HD_ + lg * 8);
  f32x4 o0 = (f32x4){0.f, 0.f, 0.f, 0.f}, o1 = (f32x4){0.f, 0.f, 0.f, 0.f};
  float lsum = 0.f;
  for (int t0 = 0; t0 < TOPK_; t0 += 64) {
    f32x4 sc[4];
#pragma unroll
    for (int f = 0; f < 4; f++) {
      short8 kf = *(const short8*)(kvk + ((long)(b * TOPK_ + t0 + f * 16 + lr)) * E_ + h * HD_ + lg * 8);
      f32x4 z = (f32x4){0.f, 0.f, 0.f, 0.f};
      sc[f] = __builtin_amdgcn_mfma_f32_16x16x32_bf16(kf, qf, z, 0, 0, 0);  // D[token][q]
    }
    float csum = 0.f;
#pragma unroll
    for (int f = 0; f < 4; f++) {
      float e0 = __expf(sc[f][0]), e1 = __expf(sc[f][1]), e2 = __expf(sc[f][2]), e3 = __expf(sc[f][3]);
      csum += (e0 + e1) + (e2 + e3);
      u32x2 w;
      w.x = (unsigned)f2bf(e0) | ((unsigned)f2bf(e1) << 16);
      w.y = (unsigned)f2bf(e2) | ((unsigned)f2bf(e3) << 16);
      *(u32x2*)(pt + lr * 128 + ((((f * 2 + (lg >> 1)) ^ (lr & 7))) << 4) + (lg & 1) * 8) = w;
    }
    csum += __shfl_xor(csum, 16);
    csum += __shfl_xor(csum, 32);
    lsum += csum;
#pragma unroll
    for (int ks = 0; ks < 2; ks++) {
      short8 pf = *(const short8*)(pt + lr * 128 + (((ks * 4 + lg) ^ (lr & 7)) << 4));
      {
        short8 vf = *(const short8*)(vt + ((long)(b * 256 + h * HD_ + 0 + lr)) * 512 + t0 + ks * 32 + lg * 8);
        o0 = __builtin_amdgcn_mfma_f32_16x16x32_bf16(pf, vf, o0, 0, 0, 0);
      }
      {
        short8 vf = *(const short8*)(vt + ((long)(b * 256 + h * HD_ + 16 + lr)) * 512 + t0 + ks * 32 + lg * 8);
        o1 = __builtin_amdgcn_mfma_f32_16x16x32_bf16(pf, vf, o1, 0, 0, 0);
      }
    }
  }
#pragma unroll
  for (int r = 0; r < 4; r++) {
    float li = 1.0f / __shfl(lsum, lg * 4 + r);
    long base = ((long)(b * L_ + q0 + lg * 4 + r)) * 512 + h * 64;
    float v0 = o0[r] * li, v1 = o1[r] * li;
    unsigned short h0 = f2bf(v0), h1 = f2bf(v1);
    ctxd[base + lr] = h0;
    ctxd[base + 32 + lr] = f2bf(v0 - bf2f(h0));
    ctxd[base + 16 + lr] = h1;
    ctxd[base + 48 + lr] = f2bf(v1 - bf2f(h1));
  }
}

extern "C" void kernel_launch(void* const* d_in, const int* in_sizes, int n_in, void* d_out, int out_size, void* d_ws,
                              size_t ws_size, hipStream_t stream) {
  (void)in_sizes; (void)n_in; (void)out_size; (void)ws_size;
  const float* qs_in = (const float*)d_in[0];
  const float* ctx_in = (const float*)d_in[1];
  const int* rind = (const int*)d_in[2];
  const float* ipw = (const float*)d_in[3];
  const float* ipb = (const float*)d_in[4];
  const float* opw = (const float*)d_in[5];
  const float* opb = (const float*)d_in[6];
  const float* c1w = (const float*)d_in[7];
  const float* c1b = (const float*)d_in[8];
  const float* g1 = (const float*)d_in[9];
  const float* b1 = (const float*)d_in[10];
  const float* mu1 = (const float*)d_in[11];
  const float* v1 = (const float*)d_in[12];
  const float* c2w = (const float*)d_in[13];
  const float* c2b = (const float*)d_in[14];
  const float* g2 = (const float*)d_in[15];
  const float* b2 = (const float*)d_in[16];
  const float* mu2 = (const float*)d_in[17];
  const float* v2 = (const float*)d_in[18];
  float* out = (float*)d_out;
  float* ws = (float*)d_ws;

  // ---- workspace layout (float offsets; 1MB = 262144 floats), peak ~74MB ----
  unsigned short* ctxd = (unsigned short*)ws;                 // [0,16) duo, written by attn
  float* Kt = ws + 4194304;                                   // [16,32) fp32; dead after ksel gather
  float* X = ws + 4194304;                                    // [16,32) fp32, written by out-proj
  unsigned short* Qt_bf = (unsigned short*)(ws + 8388608);    // [32,40) bf16; dead after q-proj
  unsigned short* X_bf = (unsigned short*)(ws + 8388608);     // [32,40) bf16, written by out-proj
  float* Qsbuf = ws + 10485760;                               // [40,42)
  unsigned* md = (unsigned*)(ws + 11010048);                  // [42,42.06)
  unsigned* idxsel = (unsigned*)(ws + 11026432);              // 8KB
  unsigned short* ksel_bf = (unsigned short*)(ws + 11272192); // [43,44)
  unsigned short* q_bf = (unsigned short*)(ws + 11534336);    // [44,52)
  unsigned short* kv_k = (unsigned short*)(ws + 13631488);    // [52,53)
  unsigned short* v_t = (unsigned short*)(ws + 13893632);     // [53,54)
  unsigned short* H = (unsigned short*)(ws + 10485760);       // [40,72) bf16 hidden (overlays dead bufs)
  unsigned short* wq_bf = (unsigned short*)(ws + 18874368);   // [72,...)
  unsigned short* wkv_bf = (unsigned short*)(ws + 18907136);
  unsigned short* c1w_bf = (unsigned short*)(ws + 18972672);
  unsigned short* c2w_bf = (unsigned short*)(ws + 19103744);
  unsigned short* opw_d = (unsigned short*)(ws + 19234816);

  const float qscale = 0.17677669529663687f;  // 1/sqrt(32)

  // fused setup: weight converts + md init + transposes + Qsbuf gather (Qt fp32 eliminated)
  k_setup<<<9184, 256, 0, stream>>>(ipw, opw, c1w, c2w, qs_in, ctx_in, rind, wq_bf, wkv_bf, c1w_bf, c2w_bf, opw_d,
                                    md, Qt_bf, Kt, Qsbuf);
  // merged q-projection (blocks [0,512), overlaps) + min-L1 distance (blocks [512,2560))
  k_dist_qp<<<2560, 256, 0, stream>>>(Kt, Qsbuf, md, Qt_bf, wq_bf, q_bf, ipb, qscale);
  // exact top-512 selection (unordered set + stable-index ties == argsort[:512] set)
  k_select<<<4, 1024, 0, stream>>>(md, idxsel);
  k_gather_bf<<<512, 256, 0, stream>>>(Kt, (const int*)idxsel, ksel_bf, TOPK_);
  // k/v projection -> kv_k + v_t
  k_gemm_s<64, 1><<<dim3(8, 16), 256, 0, stream>>>(ksel_bf, wkv_bf, 256, 512, 1.f, ipb + 256, nullptr, nullptr,
                                                   nullptr, nullptr, nullptr, nullptr, kv_k, v_t);
  // attention -> ctx duo
  k_attn_mfma<<<dim3(64, NH_, B_), 256, 0, stream>>>(q_bf, kv_k, v_t, ctxd);
  // out projection (duo x duo) -> X fp32 + X_bf
  k_gemm_d<<<dim3(4, 128), 256, 0, stream>>>(ctxd, opw_d, 256, opb, X, X_bf);
  // conv1 + bn + relu -> H bf16
  k_gemm_s<128, 3><<<dim3(8, 128), 256, 0, stream>>>(X_bf, c1w_bf, 256, 1024, 1.f, c1b, g1, b1, mu1, v1, nullptr,
                                                     nullptr, H, nullptr);
  // conv2 + bn + residual + transpose -> out
  k_gemm_s<64, 5><<<dim3(4, 128), 256, 0, stream>>>(H, c2w_bf, 1024, 256, 1.f, c2b, g2, b2, mu2, v2, X, out,
                                                    nullptr, nullptr);
}

// Round 17
// 285.925 us; speedup vs baseline: 1.0312x; 1.0312x over previous
//
#include <hip/hip_runtime.h>
#include <math.h>

#define B_ 4
#define C_ 256
#define L_ 4096
#define E_ 256
#define NH_ 8
#define HD_ 32
#define TOPK_ 512
#define MLP_ 1024
#define EPS_ 1e-5f

#if __has_attribute(amdgpu_agpr_alloc)
#define NO_AGPR __attribute__((amdgpu_agpr_alloc(0)))
#else
#define NO_AGPR
#endif

typedef __attribute__((ext_vector_type(4))) float f32x4;
typedef __attribute__((ext_vector_type(8))) short short8;
typedef __attribute__((ext_vector_type(2))) unsigned int u32x2;
typedef __attribute__((ext_vector_type(4))) unsigned int u32x4;

// async global->LDS, 16B per lane; LDS dest must be linear in lane order (wave base + lane*16).
#define GLOAD_LDS(srcp, ldsp)                                                                     \
  __builtin_amdgcn_global_load_lds((const __attribute__((address_space(1))) void*)(srcp),         \
                                   (__attribute__((address_space(3))) void*)(ldsp), 16, 0, 0)

__device__ __forceinline__ unsigned short f2bf(float x) {
  unsigned u = __float_as_uint(x);
  return (unsigned short)((u + 0x7FFFu + ((u >> 16) & 1)) >> 16);
}
__device__ __forceinline__ float bf2f(unsigned short h) { return __uint_as_float((unsigned)h << 16); }

// 16-lane sum via DPP row rotations (fused v_add_f32_dpp: 1 VALU/level, zero DS-pipe use)
__device__ __forceinline__ float dpp_red16(float s) {
  s += __int_as_float(__builtin_amdgcn_update_dpp(0, __float_as_int(s), 0x121, 0xF, 0xF, false));  // row_ror:1
  s += __int_as_float(__builtin_amdgcn_update_dpp(0, __float_as_int(s), 0x122, 0xF, 0xF, false));  // row_ror:2
  s += __int_as_float(__builtin_amdgcn_update_dpp(0, __float_as_int(s), 0x124, 0xF, 0xF, false));  // row_ror:4
  s += __int_as_float(__builtin_amdgcn_update_dpp(0, __float_as_int(s), 0x128, 0xF, 0xF, false));  // row_ror:8
  return s;
}

__device__ __forceinline__ void conv_bf8(const float* __restrict__ W, unsigned short* __restrict__ D, int blk,
                                         int tid) {
  int i = (blk * 256 + tid) * 8;
  float4 x = *(const float4*)(W + i);
  float4 y = *(const float4*)(W + i + 4);
  u32x4 w;
  w.x = (unsigned)f2bf(x.x) | ((unsigned)f2bf(x.y) << 16);
  w.y = (unsigned)f2bf(x.z) | ((unsigned)f2bf(x.w) << 16);
  w.z = (unsigned)f2bf(y.x) | ((unsigned)f2bf(y.y) << 16);
  w.w = (unsigned)f2bf(y.z) | ((unsigned)f2bf(y.w) << 16);
  *(u32x4*)(D + i) = w;
}

// ---------------- fused setup: weight converts + md init + transposes + Qsbuf gather ----------------
// blocks [0,480): prep; [480,4576): transpose qs_in -> Qt_bf (bf16 only);
// [4576,8672): ctx_in -> Kt fp32; [8672,9184): gather Qsbuf[b][r][:] = qs_in[b][:][rind[b][r]].
__global__ __launch_bounds__(256) void k_setup(const float* __restrict__ ipw, const float* __restrict__ opw,
                                               const float* __restrict__ c1w, const float* __restrict__ c2w,
                                               const float* __restrict__ qs_in, const float* __restrict__ ctx_in,
                                               const int* __restrict__ rind,
                                               unsigned short* __restrict__ wq_bf, unsigned short* __restrict__ wkv_bf,
                                               unsigned short* __restrict__ c1w_bf, unsigned short* __restrict__ c2w_bf,
                                               unsigned short* __restrict__ opw_d, unsigned* __restrict__ md,
                                               unsigned short* __restrict__ Qt_bf, float* __restrict__ Kt,
                                               float* __restrict__ Qsbuf) {
  __shared__ float tile[32][33];
  const int bx = blockIdx.x;
  const int tid = threadIdx.x;
  if (bx < 480) {
    if (bx < 32) {
      conv_bf8(ipw, wq_bf, bx, tid);
    } else if (bx < 96) {
      conv_bf8(ipw + 65536, wkv_bf, bx - 32, tid);
    } else if (bx < 224) {
      conv_bf8(c1w, c1w_bf, bx - 96, tid);
    } else if (bx < 352) {
      conv_bf8(c2w, c2w_bf, bx - 224, tid);
    } else if (bx < 416) {
      int i = ((bx - 352) * 256 + tid) * 4;
      int k = i & 255;
      int n = i >> 8;
      float4 x = *(const float4*)(opw + i);
      unsigned short h0 = f2bf(x.x), h1 = f2bf(x.y), h2 = f2bf(x.z), h3 = f2bf(x.w);
      unsigned short l0 = f2bf(x.x - bf2f(h0)), l1 = f2bf(x.y - bf2f(h1));
      unsigned short l2 = f2bf(x.z - bf2f(h2)), l3 = f2bf(x.w - bf2f(h3));
      u32x2 hv, lv;
      hv.x = (unsigned)h0 | ((unsigned)h1 << 16); hv.y = (unsigned)h2 | ((unsigned)h3 << 16);
      lv.x = (unsigned)l0 | ((unsigned)l1 << 16); lv.y = (unsigned)l2 | ((unsigned)l3 << 16);
      unsigned short* dst = opw_d + (long)n * 512 + (k >> 5) * 64 + (k & 31);
      *(u32x2*)dst = hv;
      *(u32x2*)(dst + 32) = lv;
    } else {
      md[(bx - 416) * 256 + tid] = 0x7f800000u;
    }
    return;
  }
  if (bx >= 8672) {  // Qsbuf gather: one 64-lane group per selected row
    int gr = (bx - 8672) * 4 + (tid >> 6);
    int b = gr >> 9, r = gr & 511;
    int idx = rind[b * TOPK_ + r];
    int c0 = (tid & 63) * 4;
    float* dst = Qsbuf + ((long)b * TOPK_ + r) * C_ + c0;
    const float* src = qs_in + (long)b * C_ * L_ + idx;
#pragma unroll
    for (int i = 0; i < 4; i++) dst[i] = src[(long)(c0 + i) * L_];
    return;
  }
  int tb = bx - 480;
  const float* in;
  float* out;
  unsigned short* outbf;
  int wbf;
  if (tb < 4096) {
    in = qs_in; out = nullptr; outbf = Qt_bf; wbf = 1;
  } else {
    tb -= 4096; in = ctx_in; out = Kt; outbf = nullptr; wbf = 0;
  }
  const int x = tb & 127, y = (tb >> 7) & 7, b = tb >> 10;
  const int l0 = x * 32, c0 = y * 32;
  const int tx = tid & 31, ty = tid >> 5;
  const float* ib = in + (long)b * C_ * L_;
#pragma unroll
  for (int i = ty; i < 32; i += 8) tile[i][tx] = ib[(long)(c0 + i) * L_ + l0 + tx];
  __syncthreads();
#pragma unroll
  for (int i = ty; i < 32; i += 8) {
    float v = tile[tx][i];
    long off = (long)(l0 + i) * C_ + c0 + tx;
    if (wbf) outbf[(long)b * L_ * C_ + off] = f2bf(v);
    else out[(long)b * L_ * C_ + off] = v;
  }
}

// ---------------- gather_bf (post-selection) ----------------
__global__ __launch_bounds__(256) void k_gather_bf(const float* __restrict__ src, const int* __restrict__ ind,
                                                   unsigned short* __restrict__ dst, int nrows) {
  int gr = blockIdx.x * 4 + (threadIdx.x >> 6);
  int b = gr / nrows, r = gr % nrows;
  int c = (threadIdx.x & 63) * 4;
  int idx = ind[b * nrows + r];
  float4 x = *(const float4*)(src + ((long)b * L_ + idx) * C_ + c);
  u32x2 w;
  w.x = (unsigned)f2bf(x.x) | ((unsigned)f2bf(x.y) << 16);
  w.y = (unsigned)f2bf(x.z) | ((unsigned)f2bf(x.w) << 16);
  *(u32x2*)(dst + ((long)b * nrows + r) * C_ + c) = w;
}

// ---------------- min-L1 distance (r14 standalone, best measured 117us) ----------------
// r16 post-mortem: merging q-proj into this kernel forced VGPR 48->72, occupancy 42->30%,
// dist path 117->135us. Per-kernel regalloc makes path-union a loss -> standalone again.
// grid (64, B, 8), block 256 = 16 qslot x 16 cg; 16-token chunks stream through LDS.
__global__ __launch_bounds__(256) NO_AGPR void k_dist(const float* __restrict__ Kt, const float* __restrict__ Qs,
                                                      unsigned* __restrict__ mdbits) {
  __shared__ float Kl[16 * 256];   // 16KB token chunk
  __shared__ unsigned mdl[64];     // per-block running min (bits) for the 64 tokens
  const int b = blockIdx.y, tb = blockIdx.x, qz = blockIdx.z;
  const int tid = threadIdx.x;
  const int cg = tid & 15, qslot = tid >> 4;
  float4 Q[4][4];
  {
    const float* qbase = Qs + ((long)b * TOPK_ + qz * 64 + qslot) * C_ + cg * 4;
#pragma unroll
    for (int r = 0; r < 4; r++)
#pragma unroll
      for (int i = 0; i < 4; i++) Q[r][i] = *(const float4*)(qbase + (long)r * 16 * C_ + i * 64);
  }
  // pin Q live (anti-remat)
#pragma unroll
  for (int r = 0; r < 4; r++) {
    asm volatile("" : "+v"(Q[r][0].x), "+v"(Q[r][0].y), "+v"(Q[r][0].z), "+v"(Q[r][0].w),
                      "+v"(Q[r][1].x), "+v"(Q[r][1].y), "+v"(Q[r][1].z), "+v"(Q[r][1].w));
    asm volatile("" : "+v"(Q[r][2].x), "+v"(Q[r][2].y), "+v"(Q[r][2].z), "+v"(Q[r][2].w),
                      "+v"(Q[r][3].x), "+v"(Q[r][3].y), "+v"(Q[r][3].z), "+v"(Q[r][3].w));
  }
  if (tid < 64) mdl[tid] = 0x7f800000u;
  for (int ck = 0; ck < 4; ck++) {
    __syncthreads();
    {  // stage 16 tokens (16KB): 4 float4 per thread, coalesced
      const float4* src = (const float4*)(Kt + ((long)b * L_ + tb * 64 + ck * 16) * C_);
      float4* dst = (float4*)Kl;
#pragma unroll
      for (int j = 0; j < 4; j++) dst[tid + j * 256] = src[tid + j * 256];
    }
    __syncthreads();
    for (int t = 0; t < 16; t++) {
      const float* kp = &Kl[t * 256 + cg * 4];
      float4 k0 = *(const float4*)kp;
      float4 k1 = *(const float4*)(kp + 64);
      float4 k2 = *(const float4*)(kp + 128);
      float4 k3 = *(const float4*)(kp + 192);
      float d0, d1, d2, d3;
#define DIST_R(r, dst_)                                                                                   \
  dst_ = (((fabsf(k0.x - Q[r][0].x) + fabsf(k0.y - Q[r][0].y)) +                                          \
           (fabsf(k0.z - Q[r][0].z) + fabsf(k0.w - Q[r][0].w))) +                                         \
          ((fabsf(k1.x - Q[r][1].x) + fabsf(k1.y - Q[r][1].y)) +                                          \
           (fabsf(k1.z - Q[r][1].z) + fabsf(k1.w - Q[r][1].w)))) +                                        \
         (((fabsf(k2.x - Q[r][2].x) + fabsf(k2.y - Q[r][2].y)) +                                          \
           (fabsf(k2.z - Q[r][2].z) + fabsf(k2.w - Q[r][2].w))) +                                         \
          ((fabsf(k3.x - Q[r][3].x) + fabsf(k3.y - Q[r][3].y)) +                                          \
           (fabsf(k3.z - Q[r][3].z) + fabsf(k3.w - Q[r][3].w))))
      DIST_R(0, d0);
      DIST_R(1, d1);
      DIST_R(2, d2);
      DIST_R(3, d3);
#undef DIST_R
      d0 = dpp_red16(d0);
      d1 = dpp_red16(d1);
      d2 = dpp_red16(d2);
      d3 = dpp_red16(d3);
      float mn = fminf(fminf(d0, d1), fminf(d2, d3));
      // combine the two qslot-groups within each 32-lane half
      mn = fminf(mn, __int_as_float(__builtin_amdgcn_ds_swizzle(__float_as_int(mn), 0x401F)));
      if ((tid & 31) == 0) atomicMin(&mdl[ck * 16 + t], __float_as_uint(mn));
    }
  }
  __syncthreads();
  if (tid < 64) atomicMin(&mdbits[(long)b * L_ + tb * 64 + tid], mdl[tid]);
}

// ---------------- exact top-512 selection ----------------
__global__ __launch_bounds__(1024) void k_select(const unsigned* __restrict__ mdb, unsigned* __restrict__ idxsel) {
  __shared__ unsigned vals[4096];
  __shared__ unsigned cnts[32];
  __shared__ unsigned out_n, tie_n;
  __shared__ unsigned short ties[1024];
  const int b = blockIdx.x, tid = threadIdx.x;
  const int lane = tid & 63;
#pragma unroll
  for (int s = 0; s < 4; s++) vals[tid + s * 1024] = mdb[b * 4096 + tid + s * 1024];
  if (tid < 32) cnts[tid] = 0;
  if (tid == 0) { out_n = 0; tie_n = 0; }
  __syncthreads();
  unsigned cur = 0;
  for (int bit = 31; bit >= 0; --bit) {
    unsigned cand = cur | (1u << bit);
    int c = 0;
#pragma unroll
    for (int s = 0; s < 4; s++) {
      unsigned long long bal = __ballot(vals[tid + s * 1024] < cand);
      c += __popcll(bal);
    }
    if (lane == 0) atomicAdd(&cnts[bit], (unsigned)c);
    __syncthreads();
    if (cnts[bit] < 512u) cur = cand;  // uniform: all threads read same LDS value
  }
  const unsigned M = cur;
#pragma unroll
  for (int s = 0; s < 4; s++) {
    int i = tid + s * 1024;
    unsigned v = vals[i];
    if (v < M) {
      unsigned p = atomicAdd(&out_n, 1u);
      idxsel[b * TOPK_ + p] = (unsigned)i;
    } else if (v == M) {
      unsigned t = atomicAdd(&tie_n, 1u);
      if (t < 1024u) ties[t] = (unsigned short)i;
    }
  }
  __syncthreads();
  if (tid == 0) {
    int n1 = (int)out_n;
    int nt = (int)tie_n; if (nt > 1024) nt = 1024;
    int need = 512 - n1; if (need > nt) need = nt;
    for (int j = 0; j < need; j++) {
      int bi = 1 << 30, best = -1;
      for (int t = 0; t < nt; t++) {
        int ix = ties[t];
        if (ix < bi) { bi = ix; best = t; }
      }
      ties[best] = 0xFFFF;  // mark used (> any valid idx)
      idxsel[b * TOPK_ + n1 + j] = (unsigned)bi;
    }
  }
}

// ---------------- single-bf16 MFMA GEMM: C[m,n] = epi(sum_k A[m,k]*B[n,k]) ----------------
// Staging via global_load_lds width=16: LDS dest LINEAR (slot g = row*8 + s), global source
// PRE-SWIZZLED (chunk s ^ (row&7)); swizzled read side unchanged.
// MODE 0: (v+bias)*cscale -> bf16. MODE 1: kv dual out. MODE 3: bias+bn+relu -> bf16.
// MODE 5: bias+bn + Xres residual + transposed store -> fp32 out[b][c][l].
template <int BN, int MODE>
__global__ __launch_bounds__(256) void k_gemm_s(
    const unsigned short* __restrict__ A, const unsigned short* __restrict__ Bm, int K, int N, float cscale,
    const float* __restrict__ bias, const float* __restrict__ g, const float* __restrict__ be,
    const float* __restrict__ mu, const float* __restrict__ va, const float* __restrict__ Xres,
    float* __restrict__ Cf, unsigned short* __restrict__ Cb, unsigned short* __restrict__ Caux) {
  constexpr int NWN = (BN == 128) ? 2 : 1;
  constexpr int WR = (NWN == 2) ? 64 : 32;
  constexpr int MG = WR / 16, NG = 4;
  __shared__ __align__(16) unsigned short As[128 * 64];
  __shared__ __align__(16) unsigned short Bs[BN * 64];
  const int tid = threadIdx.x;
  const int wid = tid >> 6, lane = tid & 63, lr = lane & 15, lg = lane >> 4;
  const int wm = wid / NWN, wn = wid % NWN;
  const int row0 = wm * WR, col0 = wn * 64;
  char* AsB = (char*)As;
  char* BsB = (char*)Bs;
  f32x4 acc[MG][NG];
#pragma unroll
  for (int m = 0; m < MG; m++)
#pragma unroll
    for (int n = 0; n < NG; n++) acc[m][n] = (f32x4){0.f, 0.f, 0.f, 0.f};

  for (int k0 = 0; k0 < K; k0 += 64) {
    if (k0) __syncthreads();
    {  // stage A: 1024 16B-chunks, linear LDS, pre-swizzled source
#pragma unroll
      for (int j = 0; j < 4; j++) {
        int gix = j * 256 + tid;
        int r = gix >> 3, s = gix & 7;
        int csrc = s ^ (r & 7);
        const unsigned short* srcp = A + (long)(blockIdx.y * 128 + r) * K + k0 + csrc * 8;
        GLOAD_LDS(srcp, AsB + gix * 16);
      }
    }
    if (BN == 128) {
#pragma unroll
      for (int j = 0; j < 4; j++) {
        int gix = j * 256 + tid;
        int r = gix >> 3, s = gix & 7;
        int csrc = s ^ (r & 7);
        const unsigned short* srcp = Bm + (long)(blockIdx.x * 128 + r) * K + k0 + csrc * 8;
        GLOAD_LDS(srcp, BsB + gix * 16);
      }
    } else {
#pragma unroll
      for (int j = 0; j < 2; j++) {
        int gix = j * 256 + tid;
        int r = gix >> 3, s = gix & 7;
        int csrc = s ^ (r & 7);
        const unsigned short* srcp = Bm + (long)(blockIdx.x * 64 + r) * K + k0 + csrc * 8;
        GLOAD_LDS(srcp, BsB + gix * 16);
      }
    }
    __syncthreads();
    short8 a0[MG], a1[MG], b0[NG], b1[NG];
#pragma unroll
    for (int m = 0; m < MG; m++) {
      int rr = row0 + m * 16 + lr;
      a0[m] = *(const short8*)(AsB + rr * 128 + (((0 + lg) ^ (rr & 7)) << 4));
      a1[m] = *(const short8*)(AsB + rr * 128 + (((4 + lg) ^ (rr & 7)) << 4));
    }
#pragma unroll
    for (int n = 0; n < NG; n++) {
      int rr = col0 + n * 16 + lr;
      b0[n] = *(const short8*)(BsB + rr * 128 + (((0 + lg) ^ (rr & 7)) << 4));
      b1[n] = *(const short8*)(BsB + rr * 128 + (((4 + lg) ^ (rr & 7)) << 4));
    }
#pragma unroll
    for (int m = 0; m < MG; m++)
#pragma unroll
      for (int n = 0; n < NG; n++)
        acc[m][n] = __builtin_amdgcn_mfma_f32_16x16x32_bf16(a0[m], b0[n], acc[m][n], 0, 0, 0);
#pragma unroll
    for (int m = 0; m < MG; m++)
#pragma unroll
      for (int n = 0; n < NG; n++)
        acc[m][n] = __builtin_amdgcn_mfma_f32_16x16x32_bf16(a1[m], b1[n], acc[m][n], 0, 0, 0);
  }
  const int mbase = blockIdx.y * 128 + row0 + lg * 4;
  const int nbase = blockIdx.x * BN + col0;
#pragma unroll
  for (int n = 0; n < NG; n++) {
    int nn = nbase + n * 16 + lr;
    float bb = bias[nn];
    float inv = 0.f, sh = 0.f;
    if (MODE == 3 || MODE == 5) {
      inv = g[nn] / sqrtf(va[nn] + EPS_);
      sh = be[nn] - mu[nn] * inv;
    }
#pragma unroll
    for (int m = 0; m < MG; m++) {
#pragma unroll
      for (int r = 0; r < 4; r++) {
        int mm = mbase + m * 16 + r;
        float v = acc[m][n][r] + bb;
        if (MODE == 0) {
          Cb[(long)mm * N + nn] = f2bf(v * cscale);
        } else if (MODE == 1) {
          if (nn < 256) {
            Cb[(long)mm * 256 + nn] = f2bf(v);
          } else {
            int bi = mm >> 9, t = mm & 511;
            Caux[((long)bi * 256 + (nn - 256)) * 512 + t] = f2bf(v);
          }
        } else if (MODE == 3) {
          v = v * inv + sh;
          v = fmaxf(v, 0.f);
          Cb[(long)mm * N + nn] = f2bf(v);
        } else if (MODE == 5) {
          v = v * inv + sh + Xres[(long)mm * 256 + nn];
          int bi = mm >> 12, l = mm & 4095;
          Cf[(long)bi * (C_ * L_) + (long)nn * L_ + l] = v;
        }
      }
    }
  }
}

// ---------------- duo MFMA GEMM (out-proj only): A duo [M][2K], B duo [N][2K] ----------------
__global__ __launch_bounds__(256) void k_gemm_d(const unsigned short* __restrict__ A,
                                                const unsigned short* __restrict__ Bd, int K,
                                                const float* __restrict__ bias, float* __restrict__ Cf,
                                                unsigned short* __restrict__ Cb) {
  constexpr int MG = 2, NG = 4;
  __shared__ __align__(16) unsigned short As[128 * 64];
  __shared__ __align__(16) unsigned short Bs[64 * 64];
  const int tid = threadIdx.x;
  const int wid = tid >> 6, lane = tid & 63, lr = lane & 15, lg = lane >> 4;
  const int row0 = wid * 32;
  char* AsB = (char*)As;
  char* BsB = (char*)Bs;
  f32x4 acc[MG][NG];
#pragma unroll
  for (int m = 0; m < MG; m++)
#pragma unroll
    for (int n = 0; n < NG; n++) acc[m][n] = (f32x4){0.f, 0.f, 0.f, 0.f};

  for (int kb = 0; kb < K; kb += 32) {
    if (kb) __syncthreads();
    {  // A duo: 128 rows x 64 shorts per K-step, row stride 2K
#pragma unroll
      for (int j = 0; j < 4; j++) {
        int gix = j * 256 + tid;
        int r = gix >> 3, s = gix & 7;
        int csrc = s ^ (r & 7);
        const unsigned short* srcp = A + (long)(blockIdx.y * 128 + r) * (2 * K) + kb * 2 + csrc * 8;
        GLOAD_LDS(srcp, AsB + gix * 16);
      }
    }
    {  // B duo: 64 rows x 64 shorts, row stride 2K
#pragma unroll
      for (int j = 0; j < 2; j++) {
        int gix = j * 256 + tid;
        int r = gix >> 3, s = gix & 7;
        int csrc = s ^ (r & 7);
        const unsigned short* srcp = Bd + (long)(blockIdx.x * 64 + r) * (2 * K) + kb * 2 + csrc * 8;
        GLOAD_LDS(srcp, BsB + gix * 16);
      }
    }
    __syncthreads();
    short8 a0[MG], a1[MG], b0[NG], b1[NG];
#pragma unroll
    for (int m = 0; m < MG; m++) {
      int rr = row0 + m * 16 + lr;
      a0[m] = *(const short8*)(AsB + rr * 128 + (((0 + lg) ^ (rr & 7)) << 4));
      a1[m] = *(const short8*)(AsB + rr * 128 + (((4 + lg) ^ (rr & 7)) << 4));
    }
#pragma unroll
    for (int n = 0; n < NG; n++) {
      int rr = n * 16 + lr;
      b0[n] = *(const short8*)(BsB + rr * 128 + (((0 + lg) ^ (rr & 7)) << 4));
      b1[n] = *(const short8*)(BsB + rr * 128 + (((4 + lg) ^ (rr & 7)) << 4));
    }
#pragma unroll
    for (int m = 0; m < MG; m++)
#pragma unroll
      for (int n = 0; n < NG; n++)
        acc[m][n] = __builtin_amdgcn_mfma_f32_16x16x32_bf16(a0[m], b0[n], acc[m][n], 0, 0, 0);
#pragma unroll
    for (int m = 0; m < MG; m++)
#pragma unroll
      for (int n = 0; n < NG; n++)
        acc[m][n] = __builtin_amdgcn_mfma_f32_16x16x32_bf16(a1[m], b0[n], acc[m][n], 0, 0, 0);
#pragma unroll
    for (int m = 0; m < MG; m++)
#pragma unroll
      for (int n = 0; n < NG; n++)
        acc[m][n] = __builtin_amdgcn_mfma_f32_16x16x32_bf16(a0[m], b1[n], acc[m][n], 0, 0, 0);
  }
  const int mbase = blockIdx.y * 128 + row0 + lg * 4;
  const int nbase = blockIdx.x * 64;
#pragma unroll
  for (int n = 0; n < NG; n++) {
    int nn = nbase + n * 16 + lr;
    float bb = bias[nn];
#pragma unroll
    for (int m = 0; m < MG; m++) {
#pragma unroll
      for (int r = 0; r < 4; r++) {
        int mm = mbase + m * 16 + r;
        float v = acc[m][n][r] + bb;
        Cf[(long)mm * 256 + nn] = v;
        Cb[(long)mm * 256 + nn] = f2bf(v);
      }
    }
  }
}

// ---------------- MFMA flash attention; epilogue writes ctx in duo layout ----------------
__global__ __launch_bounds__(256) void k_attn_mfma(const unsigned short* __restrict__ qbf,
                                                   const unsigned short* __restrict__ kvk,
                                                   const unsigned short* __restrict__ vt,
                                                   unsigned short* __restrict__ ctxd) {
  __shared__ __align__(16) unsigned short PT[4 * 1024];
  const int tid = threadIdx.x, wid = tid >> 6, lane = tid & 63, lr = lane & 15, lg = lane >> 4;
  const int b = blockIdx.z, h = blockIdx.y;
  const int q0 = blockIdx.x * 64 + wid * 16;
  char* pt = (char*)(PT + wid * 1024);
  short8 qf = *(const short8*)(qbf + ((long)(b * L_ + q0 + lr)) * E_ + h * HD_ + lg * 8);
  f32x4 o0 = (f32x4){0.f, 0.f, 0.f, 0.f}, o1 = (f32x4){0.f, 0.f, 0.f, 0.f};
  float lsum = 0.f;
  for (int t0 = 0; t0 < TOPK_; t0 += 64) {
    f32x4 sc[4];
#pragma unroll
    for (int f = 0; f < 4; f++) {
      short8 kf = *(const short8*)(kvk + ((long)(b * TOPK_ + t0 + f * 16 + lr)) * E_ + h * HD_ + lg * 8);
      f32x4 z = (f32x4){0.f, 0.f, 0.f, 0.f};
      sc[f] = __builtin_amdgcn_mfma_f32_16x16x32_bf16(kf, qf, z, 0, 0, 0);  // D[token][q]
    }
    float csum = 0.f;
#pragma unroll
    for (int f = 0; f < 4; f++) {
      float e0 = __expf(sc[f][0]), e1 = __expf(sc[f][1]), e2 = __expf(sc[f][2]), e3 = __expf(sc[f][3]);
      csum += (e0 + e1) + (e2 + e3);
      u32x2 w;
      w.x = (unsigned)f2bf(e0) | ((unsigned)f2bf(e1) << 16);
      w.y = (unsigned)f2bf(e2) | ((unsigned)f2bf(e3) << 16);
      *(u32x2*)(pt + lr * 128 + ((((f * 2 + (lg >> 1)) ^ (lr & 7))) << 4) + (lg & 1) * 8) = w;
    }
    csum += __shfl_xor(csum, 16);
    csum += __shfl_xor(csum, 32);
    lsum += csum;
#pragma unroll
    for (int ks = 0; ks < 2; ks++) {
      short8 pf = *(const short8*)(pt + lr * 128 + (((ks * 4 + lg) ^ (lr & 7)) << 4));
      {
        short8 vf = *(const short8*)(vt + ((long)(b * 256 + h * HD_ + 0 + lr)) * 512 + t0 + ks * 32 + lg * 8);
        o0 = __builtin_amdgcn_mfma_f32_16x16x32_bf16(pf, vf, o0, 0, 0, 0);
      }
      {
        short8 vf = *(const short8*)(vt + ((long)(b * 256 + h * HD_ + 16 + lr)) * 512 + t0 + ks * 32 + lg * 8);
        o1 = __builtin_amdgcn_mfma_f32_16x16x32_bf16(pf, vf, o1, 0, 0, 0);
      }
    }
  }
#pragma unroll
  for (int r = 0; r < 4; r++) {
    float li = 1.0f / __shfl(lsum, lg * 4 + r);
    long base = ((long)(b * L_ + q0 + lg * 4 + r)) * 512 + h * 64;
    float v0 = o0[r] * li, v1 = o1[r] * li;
    unsigned short h0 = f2bf(v0), h1 = f2bf(v1);
    ctxd[base + lr] = h0;
    ctxd[base + 32 + lr] = f2bf(v0 - bf2f(h0));
    ctxd[base + 16 + lr] = h1;
    ctxd[base + 48 + lr] = f2bf(v1 - bf2f(h1));
  }
}

extern "C" void kernel_launch(void* const* d_in, const int* in_sizes, int n_in, void* d_out, int out_size, void* d_ws,
                              size_t ws_size, hipStream_t stream) {
  (void)in_sizes; (void)n_in; (void)out_size; (void)ws_size;
  const float* qs_in = (const float*)d_in[0];
  const float* ctx_in = (const float*)d_in[1];
  const int* rind = (const int*)d_in[2];
  const float* ipw = (const float*)d_in[3];
  const float* ipb = (const float*)d_in[4];
  const float* opw = (const float*)d_in[5];
  const float* opb = (const float*)d_in[6];
  const float* c1w = (const float*)d_in[7];
  const float* c1b = (const float*)d_in[8];
  const float* g1 = (const float*)d_in[9];
  const float* b1 = (const float*)d_in[10];
  const float* mu1 = (const float*)d_in[11];
  const float* v1 = (const float*)d_in[12];
  const float* c2w = (const float*)d_in[13];
  const float* c2b = (const float*)d_in[14];
  const float* g2 = (const float*)d_in[15];
  const float* b2 = (const float*)d_in[16];
  const float* mu2 = (const float*)d_in[17];
  const float* v2 = (const float*)d_in[18];
  float* out = (float*)d_out;
  float* ws = (float*)d_ws;

  // ---- workspace layout (float offsets; 1MB = 262144 floats), peak ~74MB ----
  unsigned short* ctxd = (unsigned short*)ws;                 // [0,16) duo, written by attn
  float* Kt = ws + 4194304;                                   // [16,32) fp32; dead after ksel gather
  float* X = ws + 4194304;                                    // [16,32) fp32, written by out-proj
  unsigned short* Qt_bf = (unsigned short*)(ws + 8388608);    // [32,40) bf16; dead after q-proj
  unsigned short* X_bf = (unsigned short*)(ws + 8388608);     // [32,40) bf16, written by out-proj
  float* Qsbuf = ws + 10485760;                               // [40,42)
  unsigned* md = (unsigned*)(ws + 11010048);                  // [42,42.06)
  unsigned* idxsel = (unsigned*)(ws + 11026432);              // 8KB
  unsigned short* ksel_bf = (unsigned short*)(ws + 11272192); // [43,44)
  unsigned short* q_bf = (unsigned short*)(ws + 11534336);    // [44,52)
  unsigned short* kv_k = (unsigned short*)(ws + 13631488);    // [52,53)
  unsigned short* v_t = (unsigned short*)(ws + 13893632);     // [53,54)
  unsigned short* H = (unsigned short*)(ws + 10485760);       // [40,72) bf16 hidden (overlays dead bufs)
  unsigned short* wq_bf = (unsigned short*)(ws + 18874368);   // [72,...)
  unsigned short* wkv_bf = (unsigned short*)(ws + 18907136);
  unsigned short* c1w_bf = (unsigned short*)(ws + 18972672);
  unsigned short* c2w_bf = (unsigned short*)(ws + 19103744);
  unsigned short* opw_d = (unsigned short*)(ws + 19234816);

  const float qscale = 0.17677669529663687f;  // 1/sqrt(32)

  // fused setup: weight converts + md init + transposes + Qsbuf gather
  k_setup<<<9184, 256, 0, stream>>>(ipw, opw, c1w, c2w, qs_in, ctx_in, rind, wq_bf, wkv_bf, c1w_bf, c2w_bf, opw_d,
                                    md, Qt_bf, Kt, Qsbuf);
  // min-L1 distance (standalone, r14 form)
  k_dist<<<dim3(64, 4, 8), 256, 0, stream>>>(Kt, Qsbuf, md);
  // exact top-512 selection (unordered set + stable-index ties == argsort[:512] set)
  k_select<<<4, 1024, 0, stream>>>(md, idxsel);
  k_gather_bf<<<512, 256, 0, stream>>>(Kt, (const int*)idxsel, ksel_bf, TOPK_);
  // q projection -> q_bf (bias + 1/sqrt(HD) folded)
  k_gemm_s<64, 0><<<dim3(4, 128), 256, 0, stream>>>(Qt_bf, wq_bf, 256, 256, qscale, ipb, nullptr, nullptr, nullptr,
                                                    nullptr, nullptr, nullptr, q_bf, nullptr);
  // k/v projection -> kv_k + v_t
  k_gemm_s<64, 1><<<dim3(8, 16), 256, 0, stream>>>(ksel_bf, wkv_bf, 256, 512, 1.f, ipb + 256, nullptr, nullptr,
                                                   nullptr, nullptr, nullptr, nullptr, kv_k, v_t);
  // attention -> ctx duo
  k_attn_mfma<<<dim3(64, NH_, B_), 256, 0, stream>>>(q_bf, kv_k, v_t, ctxd);
  // out projection (duo x duo) -> X fp32 + X_bf
  k_gemm_d<<<dim3(4, 128), 256, 0, stream>>>(ctxd, opw_d, 256, opb, X, X_bf);
  // conv1 + bn + relu -> H bf16
  k_gemm_s<128, 3><<<dim3(8, 128), 256, 0, stream>>>(X_bf, c1w_bf, 256, 1024, 1.f, c1b, g1, b1, mu1, v1, nullptr,
                                                     nullptr, H, nullptr);
  // conv2 + bn + residual + transpose -> out
  k_gemm_s<64, 5><<<dim3(4, 128), 256, 0, stream>>>(H, c2w_bf, 1024, 256, 1.f, c2b, g2, b2, mu2, v2, X, out,
                                                    nullptr, nullptr);
}

// Round 18
// 279.954 us; speedup vs baseline: 1.0532x; 1.0213x over previous
//
#include <hip/hip_runtime.h>
#include <math.h>

#define B_ 4
#define C_ 256
#define L_ 4096
#define E_ 256
#define NH_ 8
#define HD_ 32
#define TOPK_ 512
#define MLP_ 1024
#define EPS_ 1e-5f

#if __has_attribute(amdgpu_agpr_alloc)
#define NO_AGPR __attribute__((amdgpu_agpr_alloc(0)))
#else
#define NO_AGPR
#endif

typedef __attribute__((ext_vector_type(4))) float f32x4;
typedef __attribute__((ext_vector_type(8))) short short8;
typedef __attribute__((ext_vector_type(2))) unsigned int u32x2;
typedef __attribute__((ext_vector_type(4))) unsigned int u32x4;

// async global->LDS, 16B per lane; LDS dest must be linear in lane order (wave base + lane*16).
#define GLOAD_LDS(srcp, ldsp)                                                                     \
  __builtin_amdgcn_global_load_lds((const __attribute__((address_space(1))) void*)(srcp),         \
                                   (__attribute__((address_space(3))) void*)(ldsp), 16, 0, 0)

__device__ __forceinline__ unsigned short f2bf(float x) {
  unsigned u = __float_as_uint(x);
  return (unsigned short)((u + 0x7FFFu + ((u >> 16) & 1)) >> 16);
}
__device__ __forceinline__ float bf2f(unsigned short h) { return __uint_as_float((unsigned)h << 16); }

// 16-lane sum via DPP row rotations (fused v_add_f32_dpp: 1 VALU/level, zero DS-pipe use)
__device__ __forceinline__ float dpp_red16(float s) {
  s += __int_as_float(__builtin_amdgcn_update_dpp(0, __float_as_int(s), 0x121, 0xF, 0xF, false));  // row_ror:1
  s += __int_as_float(__builtin_amdgcn_update_dpp(0, __float_as_int(s), 0x122, 0xF, 0xF, false));  // row_ror:2
  s += __int_as_float(__builtin_amdgcn_update_dpp(0, __float_as_int(s), 0x124, 0xF, 0xF, false));  // row_ror:4
  s += __int_as_float(__builtin_amdgcn_update_dpp(0, __float_as_int(s), 0x128, 0xF, 0xF, false));  // row_ror:8
  return s;
}

__device__ __forceinline__ void conv_bf8(const float* __restrict__ W, unsigned short* __restrict__ D, int blk,
                                         int tid) {
  int i = (blk * 256 + tid) * 8;
  float4 x = *(const float4*)(W + i);
  float4 y = *(const float4*)(W + i + 4);
  u32x4 w;
  w.x = (unsigned)f2bf(x.x) | ((unsigned)f2bf(x.y) << 16);
  w.y = (unsigned)f2bf(x.z) | ((unsigned)f2bf(x.w) << 16);
  w.z = (unsigned)f2bf(y.x) | ((unsigned)f2bf(y.y) << 16);
  w.w = (unsigned)f2bf(y.z) | ((unsigned)f2bf(y.w) << 16);
  *(u32x4*)(D + i) = w;
}

// ---------------- fused setup: weight converts + md init + BOTH input transposes ----------------
// blocks [0,480): prep; [480,4576): transpose qs_in -> Qt (+bf16); [4576,8672): ctx_in -> Kt.
__global__ __launch_bounds__(256) void k_setup(const float* __restrict__ ipw, const float* __restrict__ opw,
                                               const float* __restrict__ c1w, const float* __restrict__ c2w,
                                               const float* __restrict__ qs_in, const float* __restrict__ ctx_in,
                                               unsigned short* __restrict__ wq_bf, unsigned short* __restrict__ wkv_bf,
                                               unsigned short* __restrict__ c1w_bf, unsigned short* __restrict__ c2w_bf,
                                               unsigned short* __restrict__ opw_d, unsigned* __restrict__ md,
                                               float* __restrict__ Qt, unsigned short* __restrict__ Qt_bf,
                                               float* __restrict__ Kt) {
  __shared__ float tile[32][33];
  const int bx = blockIdx.x;
  const int tid = threadIdx.x;
  if (bx < 480) {
    if (bx < 32) {
      conv_bf8(ipw, wq_bf, bx, tid);
    } else if (bx < 96) {
      conv_bf8(ipw + 65536, wkv_bf, bx - 32, tid);
    } else if (bx < 224) {
      conv_bf8(c1w, c1w_bf, bx - 96, tid);
    } else if (bx < 352) {
      conv_bf8(c2w, c2w_bf, bx - 224, tid);
    } else if (bx < 416) {
      int i = ((bx - 352) * 256 + tid) * 4;
      int k = i & 255;
      int n = i >> 8;
      float4 x = *(const float4*)(opw + i);
      unsigned short h0 = f2bf(x.x), h1 = f2bf(x.y), h2 = f2bf(x.z), h3 = f2bf(x.w);
      unsigned short l0 = f2bf(x.x - bf2f(h0)), l1 = f2bf(x.y - bf2f(h1));
      unsigned short l2 = f2bf(x.z - bf2f(h2)), l3 = f2bf(x.w - bf2f(h3));
      u32x2 hv, lv;
      hv.x = (unsigned)h0 | ((unsigned)h1 << 16); hv.y = (unsigned)h2 | ((unsigned)h3 << 16);
      lv.x = (unsigned)l0 | ((unsigned)l1 << 16); lv.y = (unsigned)l2 | ((unsigned)l3 << 16);
      unsigned short* dst = opw_d + (long)n * 512 + (k >> 5) * 64 + (k & 31);
      *(u32x2*)dst = hv;
      *(u32x2*)(dst + 32) = lv;
    } else {
      md[(bx - 416) * 256 + tid] = 0x7f800000u;
    }
    return;
  }
  int tb = bx - 480;
  const float* in;
  float* out;
  unsigned short* outbf;
  int wbf;
  if (tb < 4096) {
    in = qs_in; out = Qt; outbf = Qt_bf; wbf = 1;
  } else {
    tb -= 4096; in = ctx_in; out = Kt; outbf = nullptr; wbf = 0;
  }
  const int x = tb & 127, y = (tb >> 7) & 7, b = tb >> 10;
  const int l0 = x * 32, c0 = y * 32;
  const int tx = tid & 31, ty = tid >> 5;
  const float* ib = in + (long)b * C_ * L_;
  float* ob = out + (long)b * L_ * C_;
#pragma unroll
  for (int i = ty; i < 32; i += 8) tile[i][tx] = ib[(long)(c0 + i) * L_ + l0 + tx];
  __syncthreads();
#pragma unroll
  for (int i = ty; i < 32; i += 8) {
    float v = tile[tx][i];
    long off = (long)(l0 + i) * C_ + c0 + tx;
    ob[off] = v;
    if (wbf) outbf[(long)b * L_ * C_ + off] = f2bf(v);
  }
}

// ---------------- gathers ----------------
__global__ __launch_bounds__(256) void k_gather_f32(const float* __restrict__ src, const int* __restrict__ ind,
                                                    float* __restrict__ dst, int nrows) {
  int gr = blockIdx.x * 4 + (threadIdx.x >> 6);
  int b = gr / nrows, r = gr % nrows;
  int c = (threadIdx.x & 63) * 4;
  int idx = ind[b * nrows + r];
  *(float4*)(dst + ((long)b * nrows + r) * C_ + c) = *(const float4*)(src + ((long)b * L_ + idx) * C_ + c);
}

__global__ __launch_bounds__(256) void k_gather_bf(const float* __restrict__ src, const int* __restrict__ ind,
                                                   unsigned short* __restrict__ dst, int nrows) {
  int gr = blockIdx.x * 4 + (threadIdx.x >> 6);
  int b = gr / nrows, r = gr % nrows;
  int c = (threadIdx.x & 63) * 4;
  int idx = ind[b * nrows + r];
  float4 x = *(const float4*)(src + ((long)b * L_ + idx) * C_ + c);
  u32x2 w;
  w.x = (unsigned)f2bf(x.x) | ((unsigned)f2bf(x.y) << 16);
  w.y = (unsigned)f2bf(x.z) | ((unsigned)f2bf(x.w) << 16);
  *(u32x2*)(dst + ((long)b * nrows + r) * C_ + c) = w;
}

// ---------------- min-L1 distance (r10 form, best measured 117us): Q-in-regs, K streamed ----------------
// Thread (qslot,cg): 4 q-rows x 16 ch in regs; 16-token chunks stream through LDS; each token
// slice (4 broadcast ds_read_b128) amortized over 4 q-rows. DPP-16 reduction, swizzle min,
// per-block md + one global atomicMin per token. grid (64, B, 8), block 256 = 16 qslot x 16 cg.
__global__ __launch_bounds__(256) NO_AGPR void k_dist(const float* __restrict__ Kt, const float* __restrict__ Qs,
                                                      unsigned* __restrict__ mdbits) {
  __shared__ float Kl[16 * 256];   // 16KB token chunk
  __shared__ unsigned mdl[64];     // per-block running min (bits) for the 64 tokens
  const int b = blockIdx.y, tb = blockIdx.x, qz = blockIdx.z;
  const int tid = threadIdx.x;
  const int cg = tid & 15, qslot = tid >> 4;
  float4 Q[4][4];
  {
    const float* qbase = Qs + ((long)b * TOPK_ + qz * 64 + qslot) * C_ + cg * 4;
#pragma unroll
    for (int r = 0; r < 4; r++)
#pragma unroll
      for (int i = 0; i < 4; i++) Q[r][i] = *(const float4*)(qbase + (long)r * 16 * C_ + i * 64);
  }
  // pin Q live (anti-remat)
#pragma unroll
  for (int r = 0; r < 4; r++) {
    asm volatile("" : "+v"(Q[r][0].x), "+v"(Q[r][0].y), "+v"(Q[r][0].z), "+v"(Q[r][0].w),
                      "+v"(Q[r][1].x), "+v"(Q[r][1].y), "+v"(Q[r][1].z), "+v"(Q[r][1].w));
    asm volatile("" : "+v"(Q[r][2].x), "+v"(Q[r][2].y), "+v"(Q[r][2].z), "+v"(Q[r][2].w),
                      "+v"(Q[r][3].x), "+v"(Q[r][3].y), "+v"(Q[r][3].z), "+v"(Q[r][3].w));
  }
  if (tid < 64) mdl[tid] = 0x7f800000u;
  for (int ck = 0; ck < 4; ck++) {
    __syncthreads();
    {  // stage 16 tokens (16KB): 4 float4 per thread, coalesced
      const float4* src = (const float4*)(Kt + ((long)b * L_ + tb * 64 + ck * 16) * C_);
      float4* dst = (float4*)Kl;
#pragma unroll
      for (int j = 0; j < 4; j++) dst[tid + j * 256] = src[tid + j * 256];
    }
    __syncthreads();
    for (int t = 0; t < 16; t++) {
      const float* kp = &Kl[t * 256 + cg * 4];
      float4 k0 = *(const float4*)kp;
      float4 k1 = *(const float4*)(kp + 64);
      float4 k2 = *(const float4*)(kp + 128);
      float4 k3 = *(const float4*)(kp + 192);
      float d0, d1, d2, d3;
#define DIST_R(r, dst_)                                                                                   \
  dst_ = (((fabsf(k0.x - Q[r][0].x) + fabsf(k0.y - Q[r][0].y)) +                                          \
           (fabsf(k0.z - Q[r][0].z) + fabsf(k0.w - Q[r][0].w))) +                                         \
          ((fabsf(k1.x - Q[r][1].x) + fabsf(k1.y - Q[r][1].y)) +                                          \
           (fabsf(k1.z - Q[r][1].z) + fabsf(k1.w - Q[r][1].w)))) +                                        \
         (((fabsf(k2.x - Q[r][2].x) + fabsf(k2.y - Q[r][2].y)) +                                          \
           (fabsf(k2.z - Q[r][2].z) + fabsf(k2.w - Q[r][2].w))) +                                         \
          ((fabsf(k3.x - Q[r][3].x) + fabsf(k3.y - Q[r][3].y)) +                                          \
           (fabsf(k3.z - Q[r][3].z) + fabsf(k3.w - Q[r][3].w))))
      DIST_R(0, d0);
      DIST_R(1, d1);
      DIST_R(2, d2);
      DIST_R(3, d3);
#undef DIST_R
      d0 = dpp_red16(d0);
      d1 = dpp_red16(d1);
      d2 = dpp_red16(d2);
      d3 = dpp_red16(d3);
      float mn = fminf(fminf(d0, d1), fminf(d2, d3));
      // combine the two qslot-groups within each 32-lane half
      mn = fminf(mn, __int_as_float(__builtin_amdgcn_ds_swizzle(__float_as_int(mn), 0x401F)));
      if ((tid & 31) == 0) atomicMin(&mdl[ck * 16 + t], __float_as_uint(mn));
    }
  }
  __syncthreads();
  if (tid < 64) atomicMin(&mdbits[(long)b * L_ + tb * 64 + tid], mdl[tid]);
}

// ---------------- exact top-512 selection ----------------
__global__ __launch_bounds__(1024) void k_select(const unsigned* __restrict__ mdb, unsigned* __restrict__ idxsel) {
  __shared__ unsigned vals[4096];
  __shared__ unsigned cnts[32];
  __shared__ unsigned out_n, tie_n;
  __shared__ unsigned short ties[1024];
  const int b = blockIdx.x, tid = threadIdx.x;
  const int lane = tid & 63;
#pragma unroll
  for (int s = 0; s < 4; s++) vals[tid + s * 1024] = mdb[b * 4096 + tid + s * 1024];
  if (tid < 32) cnts[tid] = 0;
  if (tid == 0) { out_n = 0; tie_n = 0; }
  __syncthreads();
  unsigned cur = 0;
  for (int bit = 31; bit >= 0; --bit) {
    unsigned cand = cur | (1u << bit);
    int c = 0;
#pragma unroll
    for (int s = 0; s < 4; s++) {
      unsigned long long bal = __ballot(vals[tid + s * 1024] < cand);
      c += __popcll(bal);
    }
    if (lane == 0) atomicAdd(&cnts[bit], (unsigned)c);
    __syncthreads();
    if (cnts[bit] < 512u) cur = cand;  // uniform: all threads read same LDS value
  }
  const unsigned M = cur;
#pragma unroll
  for (int s = 0; s < 4; s++) {
    int i = tid + s * 1024;
    unsigned v = vals[i];
    if (v < M) {
      unsigned p = atomicAdd(&out_n, 1u);
      idxsel[b * TOPK_ + p] = (unsigned)i;
    } else if (v == M) {
      unsigned t = atomicAdd(&tie_n, 1u);
      if (t < 1024u) ties[t] = (unsigned short)i;
    }
  }
  __syncthreads();
  if (tid == 0) {
    int n1 = (int)out_n;
    int nt = (int)tie_n; if (nt > 1024) nt = 1024;
    int need = 512 - n1; if (need > nt) need = nt;
    for (int j = 0; j < need; j++) {
      int bi = 1 << 30, best = -1;
      for (int t = 0; t < nt; t++) {
        int ix = ties[t];
        if (ix < bi) { bi = ix; best = t; }
      }
      ties[best] = 0xFFFF;  // mark used (> any valid idx)
      idxsel[b * TOPK_ + n1 + j] = (unsigned)bi;
    }
  }
}

// ---------------- single-bf16 MFMA GEMM: C[m,n] = epi(sum_k A[m,k]*B[n,k]) ----------------
// Staging via global_load_lds width=16: LDS dest LINEAR (slot g = row*8 + s), global source
// PRE-SWIZZLED (chunk s ^ (row&7)); swizzled read side unchanged (rule #21).
// MODE 0: (v+bias)*cscale -> bf16. MODE 1: kv dual out. MODE 3: bias+bn+relu -> bf16.
// MODE 5: bias+bn + Xres residual + transposed store -> fp32 out[b][c][l].
template <int BN, int MODE>
__global__ __launch_bounds__(256) void k_gemm_s(
    const unsigned short* __restrict__ A, const unsigned short* __restrict__ Bm, int K, int N, float cscale,
    const float* __restrict__ bias, const float* __restrict__ g, const float* __restrict__ be,
    const float* __restrict__ mu, const float* __restrict__ va, const float* __restrict__ Xres,
    float* __restrict__ Cf, unsigned short* __restrict__ Cb, unsigned short* __restrict__ Caux) {
  constexpr int NWN = (BN == 128) ? 2 : 1;
  constexpr int WR = (NWN == 2) ? 64 : 32;
  constexpr int MG = WR / 16, NG = 4;
  __shared__ __align__(16) unsigned short As[128 * 64];
  __shared__ __align__(16) unsigned short Bs[BN * 64];
  const int tid = threadIdx.x;
  const int wid = tid >> 6, lane = tid & 63, lr = lane & 15, lg = lane >> 4;
  const int wm = wid / NWN, wn = wid % NWN;
  const int row0 = wm * WR, col0 = wn * 64;
  char* AsB = (char*)As;
  char* BsB = (char*)Bs;
  f32x4 acc[MG][NG];
#pragma unroll
  for (int m = 0; m < MG; m++)
#pragma unroll
    for (int n = 0; n < NG; n++) acc[m][n] = (f32x4){0.f, 0.f, 0.f, 0.f};

  for (int k0 = 0; k0 < K; k0 += 64) {
    if (k0) __syncthreads();
    {  // stage A: 1024 16B-chunks, linear LDS, pre-swizzled source
#pragma unroll
      for (int j = 0; j < 4; j++) {
        int gix = j * 256 + tid;
        int r = gix >> 3, s = gix & 7;
        int csrc = s ^ (r & 7);
        const unsigned short* srcp = A + (long)(blockIdx.y * 128 + r) * K + k0 + csrc * 8;
        GLOAD_LDS(srcp, AsB + gix * 16);
      }
    }
    if (BN == 128) {
#pragma unroll
      for (int j = 0; j < 4; j++) {
        int gix = j * 256 + tid;
        int r = gix >> 3, s = gix & 7;
        int csrc = s ^ (r & 7);
        const unsigned short* srcp = Bm + (long)(blockIdx.x * 128 + r) * K + k0 + csrc * 8;
        GLOAD_LDS(srcp, BsB + gix * 16);
      }
    } else {
#pragma unroll
      for (int j = 0; j < 2; j++) {
        int gix = j * 256 + tid;
        int r = gix >> 3, s = gix & 7;
        int csrc = s ^ (r & 7);
        const unsigned short* srcp = Bm + (long)(blockIdx.x * 64 + r) * K + k0 + csrc * 8;
        GLOAD_LDS(srcp, BsB + gix * 16);
      }
    }
    __syncthreads();
    short8 a0[MG], a1[MG], b0[NG], b1[NG];
#pragma unroll
    for (int m = 0; m < MG; m++) {
      int rr = row0 + m * 16 + lr;
      a0[m] = *(const short8*)(AsB + rr * 128 + (((0 + lg) ^ (rr & 7)) << 4));
      a1[m] = *(const short8*)(AsB + rr * 128 + (((4 + lg) ^ (rr & 7)) << 4));
    }
#pragma unroll
    for (int n = 0; n < NG; n++) {
      int rr = col0 + n * 16 + lr;
      b0[n] = *(const short8*)(BsB + rr * 128 + (((0 + lg) ^ (rr & 7)) << 4));
      b1[n] = *(const short8*)(BsB + rr * 128 + (((4 + lg) ^ (rr & 7)) << 4));
    }
#pragma unroll
    for (int m = 0; m < MG; m++)
#pragma unroll
      for (int n = 0; n < NG; n++)
        acc[m][n] = __builtin_amdgcn_mfma_f32_16x16x32_bf16(a0[m], b0[n], acc[m][n], 0, 0, 0);
#pragma unroll
    for (int m = 0; m < MG; m++)
#pragma unroll
      for (int n = 0; n < NG; n++)
        acc[m][n] = __builtin_amdgcn_mfma_f32_16x16x32_bf16(a1[m], b1[n], acc[m][n], 0, 0, 0);
  }
  const int mbase = blockIdx.y * 128 + row0 + lg * 4;
  const int nbase = blockIdx.x * BN + col0;
#pragma unroll
  for (int n = 0; n < NG; n++) {
    int nn = nbase + n * 16 + lr;
    float bb = bias[nn];
    float inv = 0.f, sh = 0.f;
    if (MODE == 3 || MODE == 5) {
      inv = g[nn] / sqrtf(va[nn] + EPS_);
      sh = be[nn] - mu[nn] * inv;
    }
#pragma unroll
    for (int m = 0; m < MG; m++) {
#pragma unroll
      for (int r = 0; r < 4; r++) {
        int mm = mbase + m * 16 + r;
        float v = acc[m][n][r] + bb;
        if (MODE == 0) {
          Cb[(long)mm * N + nn] = f2bf(v * cscale);
        } else if (MODE == 1) {
          if (nn < 256) {
            Cb[(long)mm * 256 + nn] = f2bf(v);
          } else {
            int bi = mm >> 9, t = mm & 511;
            Caux[((long)bi * 256 + (nn - 256)) * 512 + t] = f2bf(v);
          }
        } else if (MODE == 3) {
          v = v * inv + sh;
          v = fmaxf(v, 0.f);
          Cb[(long)mm * N + nn] = f2bf(v);
        } else if (MODE == 5) {
          v = v * inv + sh + Xres[(long)mm * 256 + nn];
          int bi = mm >> 12, l = mm & 4095;
          Cf[(long)bi * (C_ * L_) + (long)nn * L_ + l] = v;
        }
      }
    }
  }
}

// ---------------- duo MFMA GEMM (out-proj only): A duo [M][2K], B duo [N][2K] ----------------
__global__ __launch_bounds__(256) void k_gemm_d(const unsigned short* __restrict__ A,
                                                const unsigned short* __restrict__ Bd, int K,
                                                const float* __restrict__ bias, float* __restrict__ Cf,
                                                unsigned short* __restrict__ Cb) {
  constexpr int MG = 2, NG = 4;
  __shared__ __align__(16) unsigned short As[128 * 64];
  __shared__ __align__(16) unsigned short Bs[64 * 64];
  const int tid = threadIdx.x;
  const int wid = tid >> 6, lane = tid & 63, lr = lane & 15, lg = lane >> 4;
  const int row0 = wid * 32;
  char* AsB = (char*)As;
  char* BsB = (char*)Bs;
  f32x4 acc[MG][NG];
#pragma unroll
  for (int m = 0; m < MG; m++)
#pragma unroll
    for (int n = 0; n < NG; n++) acc[m][n] = (f32x4){0.f, 0.f, 0.f, 0.f};

  for (int kb = 0; kb < K; kb += 32) {
    if (kb) __syncthreads();
    {  // A duo: 128 rows x 64 shorts per K-step, row stride 2K
#pragma unroll
      for (int j = 0; j < 4; j++) {
        int gix = j * 256 + tid;
        int r = gix >> 3, s = gix & 7;
        int csrc = s ^ (r & 7);
        const unsigned short* srcp = A + (long)(blockIdx.y * 128 + r) * (2 * K) + kb * 2 + csrc * 8;
        GLOAD_LDS(srcp, AsB + gix * 16);
      }
    }
    {  // B duo: 64 rows x 64 shorts, row stride 2K
#pragma unroll
      for (int j = 0; j < 2; j++) {
        int gix = j * 256 + tid;
        int r = gix >> 3, s = gix & 7;
        int csrc = s ^ (r & 7);
        const unsigned short* srcp = Bd + (long)(blockIdx.x * 64 + r) * (2 * K) + kb * 2 + csrc * 8;
        GLOAD_LDS(srcp, BsB + gix * 16);
      }
    }
    __syncthreads();
    short8 a0[MG], a1[MG], b0[NG], b1[NG];
#pragma unroll
    for (int m = 0; m < MG; m++) {
      int rr = row0 + m * 16 + lr;
      a0[m] = *(const short8*)(AsB + rr * 128 + (((0 + lg) ^ (rr & 7)) << 4));
      a1[m] = *(const short8*)(AsB + rr * 128 + (((4 + lg) ^ (rr & 7)) << 4));
    }
#pragma unroll
    for (int n = 0; n < NG; n++) {
      int rr = n * 16 + lr;
      b0[n] = *(const short8*)(BsB + rr * 128 + (((0 + lg) ^ (rr & 7)) << 4));
      b1[n] = *(const short8*)(BsB + rr * 128 + (((4 + lg) ^ (rr & 7)) << 4));
    }
#pragma unroll
    for (int m = 0; m < MG; m++)
#pragma unroll
      for (int n = 0; n < NG; n++)
        acc[m][n] = __builtin_amdgcn_mfma_f32_16x16x32_bf16(a0[m], b0[n], acc[m][n], 0, 0, 0);
#pragma unroll
    for (int m = 0; m < MG; m++)
#pragma unroll
      for (int n = 0; n < NG; n++)
        acc[m][n] = __builtin_amdgcn_mfma_f32_16x16x32_bf16(a1[m], b0[n], acc[m][n], 0, 0, 0);
#pragma unroll
    for (int m = 0; m < MG; m++)
#pragma unroll
      for (int n = 0; n < NG; n++)
        acc[m][n] = __builtin_amdgcn_mfma_f32_16x16x32_bf16(a0[m], b1[n], acc[m][n], 0, 0, 0);
  }
  const int mbase = blockIdx.y * 128 + row0 + lg * 4;
  const int nbase = blockIdx.x * 64;
#pragma unroll
  for (int n = 0; n < NG; n++) {
    int nn = nbase + n * 16 + lr;
    float bb = bias[nn];
#pragma unroll
    for (int m = 0; m < MG; m++) {
#pragma unroll
      for (int r = 0; r < 4; r++) {
        int mm = mbase + m * 16 + r;
        float v = acc[m][n][r] + bb;
        Cf[(long)mm * 256 + nn] = v;
        Cb[(long)mm * 256 + nn] = f2bf(v);
      }
    }
  }
}

// ---------------- MFMA flash attention; epilogue writes ctx in duo layout ----------------
__global__ __launch_bounds__(256) void k_attn_mfma(const unsigned short* __restrict__ qbf,
                                                   const unsigned short* __restrict__ kvk,
                                                   const unsigned short* __restrict__ vt,
                                                   unsigned short* __restrict__ ctxd) {
  __shared__ __align__(16) unsigned short PT[4 * 1024];
  const int tid = threadIdx.x, wid = tid >> 6, lane = tid & 63, lr = lane & 15, lg = lane >> 4;
  const int b = blockIdx.z, h = blockIdx.y;
  const int q0 = blockIdx.x * 64 + wid * 16;
  char* pt = (char*)(PT + wid * 1024);
  short8 qf = *(const short8*)(qbf + ((long)(b * L_ + q0 + lr)) * E_ + h * HD_ + lg * 8);
  f32x4 o0 = (f32x4){0.f, 0.f, 0.f, 0.f}, o1 = (f32x4){0.f, 0.f, 0.f, 0.f};
  float lsum = 0.f;
  for (int t0 = 0; t0 < TOPK_; t0 += 64) {
    f32x4 sc[4];
#pragma unroll
    for (int f = 0; f < 4; f++) {
      short8 kf = *(const short8*)(kvk + ((long)(b * TOPK_ + t0 + f * 16 + lr)) * E_ + h * HD_ + lg * 8);
      f32x4 z = (f32x4){0.f, 0.f, 0.f, 0.f};
      sc[f] = __builtin_amdgcn_mfma_f32_16x16x32_bf16(kf, qf, z, 0, 0, 0);  // D[token][q]
    }
    float csum = 0.f;
#pragma unroll
    for (int f = 0; f < 4; f++) {
      float e0 = __expf(sc[f][0]), e1 = __expf(sc[f][1]), e2 = __expf(sc[f][2]), e3 = __expf(sc[f][3]);
      csum += (e0 + e1) + (e2 + e3);
      u32x2 w;
      w.x = (unsigned)f2bf(e0) | ((unsigned)f2bf(e1) << 16);
      w.y = (unsigned)f2bf(e2) | ((unsigned)f2bf(e3) << 16);
      *(u32x2*)(pt + lr * 128 + ((((f * 2 + (lg >> 1)) ^ (lr & 7))) << 4) + (lg & 1) * 8) = w;
    }
    csum += __shfl_xor(csum, 16);
    csum += __shfl_xor(csum, 32);
    lsum += csum;
#pragma unroll
    for (int ks = 0; ks < 2; ks++) {
      short8 pf = *(const short8*)(pt + lr * 128 + (((ks * 4 + lg) ^ (lr & 7)) << 4));
      {
        short8 vf = *(const short8*)(vt + ((long)(b * 256 + h * HD_ + 0 + lr)) * 512 + t0 + ks * 32 + lg * 8);
        o0 = __builtin_amdgcn_mfma_f32_16x16x32_bf16(pf, vf, o0, 0, 0, 0);
      }
      {
        short8 vf = *(const short8*)(vt + ((long)(b * 256 + h * HD_ + 16 + lr)) * 512 + t0 + ks * 32 + lg * 8);
        o1 = __builtin_amdgcn_mfma_f32_16x16x32_bf16(pf, vf, o1, 0, 0, 0);
      }
    }
  }
#pragma unroll
  for (int r = 0; r < 4; r++) {
    float li = 1.0f / __shfl(lsum, lg * 4 + r);
    long base = ((long)(b * L_ + q0 + lg * 4 + r)) * 512 + h * 64;
    float v0 = o0[r] * li, v1 = o1[r] * li;
    unsigned short h0 = f2bf(v0), h1 = f2bf(v1);
    ctxd[base + lr] = h0;
    ctxd[base + 32 + lr] = f2bf(v0 - bf2f(h0));
    ctxd[base + 16 + lr] = h1;
    ctxd[base + 48 + lr] = f2bf(v1 - bf2f(h1));
  }
}

extern "C" void kernel_launch(void* const* d_in, const int* in_sizes, int n_in, void* d_out, int out_size, void* d_ws,
                              size_t ws_size, hipStream_t stream) {
  (void)in_sizes; (void)n_in; (void)out_size; (void)ws_size;
  const float* qs_in = (const float*)d_in[0];
  const float* ctx_in = (const float*)d_in[1];
  const int* rind = (const int*)d_in[2];
  const float* ipw = (const float*)d_in[3];
  const float* ipb = (const float*)d_in[4];
  const float* opw = (const float*)d_in[5];
  const float* opb = (const float*)d_in[6];
  const float* c1w = (const float*)d_in[7];
  const float* c1b = (const float*)d_in[8];
  const float* g1 = (const float*)d_in[9];
  const float* b1 = (const float*)d_in[10];
  const float* mu1 = (const float*)d_in[11];
  const float* v1 = (const float*)d_in[12];
  const float* c2w = (const float*)d_in[13];
  const float* c2b = (const float*)d_in[14];
  const float* g2 = (const float*)d_in[15];
  const float* b2 = (const float*)d_in[16];
  const float* mu2 = (const float*)d_in[17];
  const float* v2 = (const float*)d_in[18];
  float* out = (float*)d_out;
  float* ws = (float*)d_ws;

  // ---- workspace layout (float offsets; 1MB = 262144 floats), peak ~74MB ----
  float* Qt = ws;                                             // [0,16)MB fp32; dead after Qsbuf gather
  unsigned short* ctxd = (unsigned short*)ws;                 // [0,16) duo, written by attn
  float* Kt = ws + 4194304;                                   // [16,32) fp32; dead after ksel gather
  float* X = ws + 4194304;                                    // [16,32) fp32, written by out-proj
  unsigned short* Qt_bf = (unsigned short*)(ws + 8388608);    // [32,40) bf16; dead after q-proj
  unsigned short* X_bf = (unsigned short*)(ws + 8388608);     // [32,40) bf16, written by out-proj
  float* Qsbuf = ws + 10485760;                               // [40,42)
  unsigned* md = (unsigned*)(ws + 11010048);                  // [42,42.06)
  unsigned* idxsel = (unsigned*)(ws + 11026432);              // 8KB
  unsigned short* ksel_bf = (unsigned short*)(ws + 11272192); // [43,44)
  unsigned short* q_bf = (unsigned short*)(ws + 11534336);    // [44,52)
  unsigned short* kv_k = (unsigned short*)(ws + 13631488);    // [52,53)
  unsigned short* v_t = (unsigned short*)(ws + 13893632);     // [53,54)
  unsigned short* H = (unsigned short*)(ws + 10485760);       // [40,72) bf16 hidden (overlays dead bufs)
  unsigned short* wq_bf = (unsigned short*)(ws + 18874368);   // [72,...)
  unsigned short* wkv_bf = (unsigned short*)(ws + 18907136);
  unsigned short* c1w_bf = (unsigned short*)(ws + 18972672);
  unsigned short* c2w_bf = (unsigned short*)(ws + 19103744);
  unsigned short* opw_d = (unsigned short*)(ws + 19234816);

  const float qscale = 0.17677669529663687f;  // 1/sqrt(32)

  // fused setup: weight converts + md init + both transposes
  k_setup<<<8672, 256, 0, stream>>>(ipw, opw, c1w, c2w, qs_in, ctx_in, wq_bf, wkv_bf, c1w_bf, c2w_bf, opw_d, md, Qt,
                                    Qt_bf, Kt);
  k_gather_f32<<<512, 256, 0, stream>>>(Qt, rind, Qsbuf, TOPK_);
  k_dist<<<dim3(64, 4, 8), 256, 0, stream>>>(Kt, Qsbuf, md);
  // exact top-512 selection (unordered set + stable-index ties == argsort[:512] set)
  k_select<<<4, 1024, 0, stream>>>(md, idxsel);
  k_gather_bf<<<512, 256, 0, stream>>>(Kt, (const int*)idxsel, ksel_bf, TOPK_);

  // q projection -> q_bf (bias + 1/sqrt(HD) folded)
  k_gemm_s<64, 0><<<dim3(4, 128), 256, 0, stream>>>(Qt_bf, wq_bf, 256, 256, qscale, ipb, nullptr, nullptr, nullptr,
                                                    nullptr, nullptr, nullptr, q_bf, nullptr);
  // k/v projection -> kv_k + v_t
  k_gemm_s<64, 1><<<dim3(8, 16), 256, 0, stream>>>(ksel_bf, wkv_bf, 256, 512, 1.f, ipb + 256, nullptr, nullptr,
                                                   nullptr, nullptr, nullptr, nullptr, kv_k, v_t);
  // attention -> ctx duo
  k_attn_mfma<<<dim3(64, NH_, B_), 256, 0, stream>>>(q_bf, kv_k, v_t, ctxd);
  // out projection (duo x duo) -> X fp32 + X_bf
  k_gemm_d<<<dim3(4, 128), 256, 0, stream>>>(ctxd, opw_d, 256, opb, X, X_bf);
  // conv1 + bn + relu -> H bf16
  k_gemm_s<128, 3><<<dim3(8, 128), 256, 0, stream>>>(X_bf, c1w_bf, 256, 1024, 1.f, c1b, g1, b1, mu1, v1, nullptr,
                                                     nullptr, H, nullptr);
  // conv2 + bn + residual + transpose -> out
  k_gemm_s<64, 5><<<dim3(4, 128), 256, 0, stream>>>(H, c2w_bf, 1024, 256, 1.f, c2b, g2, b2, mu2, v2, X, out,
                                                    nullptr, nullptr);
}